// Round 3
// baseline (18746.609 us; speedup 1.0000x reference)
//
#include <hip/hip_runtime.h>

// ============================================================================
// ModelMRM: fused masked-reconstruction transformer forward (MI355X/gfx950)
// Dtype contract (evidence, rounds 0-2):
//   - float inputs f32 (in_npz 7.49MB), masks int32
//   - d_out is f32 (out_npz 2.68MB > bf16 raw size): [loss(1), y(B*L*P*2)]
// Design: 1 block (256 thr) per sequence (P=32 tokens, E=128). Residual x,
// temps in LDS (f32). Weights read from global (L2/L3-resident, ~3.5MB f32).
// ============================================================================

#define NP 32
#define NE 128
#define NL 256
#define NB 64
#define NSEQ (NB * NL)
#define NHEADS 8
#define NHD 16
#define NMLP 512
#define NDEPTH 4
#define LST 132   // LDS row stride (floats): 128 + 4 pad, float4-aligned

typedef unsigned int u32;

__device__ __forceinline__ float gelu_f(float x) {  // exact gelu (approximate=False)
  return 0.5f * x * (1.0f + erff(x * 0.7071067811865475f));
}

struct Args {
  const float *pos, *ctr, *ang;
  const int *sel;
  const float *Wp, *bp, *Wpe1, *bpe1, *Wpe2, *bpe2, *ltype, *mtok;
  const float *Wqkv, *bqkv, *Wo, *bo, *ln1s, *ln1b, *Wm1, *bm1, *Wm2, *bm2;
  const float *ln2s, *ln2b, *lnfs, *lnfb, *Wd1, *bd1, *Wd2, *bd2;
  float* out;
  float* wsf;
  int* wsi;
};

// acc[4][4] += src[32x128 LDS] @ W[128 x ldw f32, cols cabs..cabs+3]
__device__ __forceinline__ void mm128(const float* __restrict__ src,
                                      const float* __restrict__ W, int ldw,
                                      int r0, int cabs, float acc[4][4]) {
#pragma unroll 4
  for (int k = 0; k < NE; ++k) {
    float4 wv = *(const float4*)(W + k * ldw + cabs);
#pragma unroll
    for (int rr = 0; rr < 4; ++rr) {
      float sv = src[(r0 + rr) * LST + k];  // LDS broadcast (uniform per half-wave)
      acc[rr][0] += sv * wv.x; acc[rr][1] += sv * wv.y;
      acc[rr][2] += sv * wv.z; acc[rr][3] += sv * wv.w;
    }
  }
}

// dst = LN(src) * gam + bet   (mean/var over 128, eps 1e-5, population var)
__device__ __forceinline__ void layer_norm(const float* __restrict__ src,
                                           float* __restrict__ dst,
                                           const float* gam, const float* bet,
                                           int t, float* mrow, float* vrow) {
  {
    int p = t >> 3, j = t & 7;  // 8 threads per row
    const float* row = src + p * LST + j * 16;
    float sum = 0.f, sq = 0.f;
#pragma unroll
    for (int k2 = 0; k2 < 16; ++k2) { float v = row[k2]; sum += v; sq += v * v; }
#pragma unroll
    for (int o = 1; o < 8; o <<= 1) { sum += __shfl_xor(sum, o); sq += __shfl_xor(sq, o); }
    if (j == 0) {
      float m = sum * 0.0078125f;
      mrow[p] = m;
      vrow[p] = sq * 0.0078125f - m * m;
    }
  }
  __syncthreads();
  {
    int rg = t >> 5, cg = t & 31, r0 = rg * 4, c0 = cg * 4;
    float4 gv = *(const float4*)(gam + c0);
    float4 bv = *(const float4*)(bet + c0);
#pragma unroll
    for (int rr = 0; rr < 4; ++rr) {
      int r = r0 + rr;
      float m = mrow[r], rs = rsqrtf(vrow[r] + 1e-5f);
      float4 v = *(const float4*)&src[r * LST + c0];
      float4 o;
      o.x = (v.x - m) * rs * gv.x + bv.x;
      o.y = (v.y - m) * rs * gv.y + bv.y;
      o.z = (v.z - m) * rs * gv.z + bv.z;
      o.w = (v.w - m) * rs * gv.w + bv.w;
      *(float4*)&dst[r * LST + c0] = o;
    }
  }
  __syncthreads();
}

__global__ __launch_bounds__(256, 2) void mrm_main(Args a) {
  __shared__ float xs[32 * LST];   // residual stream
  __shared__ float hs[32 * LST];   // LN output
  __shared__ float ts[32 * LST];   // attn-out / mlp-chunk temp
  __shared__ float qs[32 * 17];
  __shared__ float ks2[32 * 17];
  __shared__ float vs[32 * 17];
  __shared__ float ss[32 * 33];
  __shared__ float tvec[128];
  __shared__ float pvec[128];
  __shared__ float mrow[32], vrow[32], srow[32];
  __shared__ int selv[32];

  const int s = blockIdx.x;
  const int t = threadIdx.x;
  const int rg = t >> 5, cg = t & 31, r0 = rg * 4, c0 = cg * 4;

  if (t < 32) selv[t] = a.sel[s * NP + t];

  const float cx = a.ctr[s * 2 + 0];
  const float cy = a.ctr[s * 2 + 1];
  const float an = a.ang[s];
  const float ca = cosf(an), sa = sinf(an);

  // ---- positional embedding: pe = gelu(pf @ Wpe1 + bpe1) @ Wpe2 + bpe2 ----
  if (t < 128) {
    float accp = a.bpe1[t] + cx * a.Wpe1[t] + cy * a.Wpe1[128 + t]
               + ca * a.Wpe1[256 + t] + sa * a.Wpe1[384 + t];
    tvec[t] = gelu_f(accp);
  }
  __syncthreads();
  if (t < 128) {
    float accp = a.bpe2[t];
    for (int e = 0; e < 128; ++e) accp += tvec[e] * a.Wpe2[e * 128 + t];
    pvec[t] = accp;
  }
  __syncthreads();

  // ---- token build: tok = sel ? mask_token : lane_norm@Wp + bp + pe + lane_type
  {
    float4 w0v = *(const float4*)(a.Wp + c0);
    float4 w1v = *(const float4*)(a.Wp + NE + c0);
    float4 bpv = *(const float4*)(a.bp + c0);
    float4 ltv = *(const float4*)(a.ltype + c0);
    float4 mtv = *(const float4*)(a.mtok + c0);
    float a0 = bpv.x + pvec[c0 + 0] + ltv.x;
    float a1 = bpv.y + pvec[c0 + 1] + ltv.y;
    float a2 = bpv.z + pvec[c0 + 2] + ltv.z;
    float a3 = bpv.w + pvec[c0 + 3] + ltv.w;
#pragma unroll
    for (int rr = 0; rr < 4; ++rr) {
      int p = r0 + rr;
      float px = a.pos[(s * NP + p) * 2 + 0] - cx;
      float py = a.pos[(s * NP + p) * 2 + 1] - cy;
      bool mk = selv[p] != 0;
      float4 o;
      o.x = mk ? mtv.x : (px * w0v.x + py * w1v.x + a0);
      o.y = mk ? mtv.y : (px * w0v.y + py * w1v.y + a1);
      o.z = mk ? mtv.z : (px * w0v.z + py * w1v.z + a2);
      o.w = mk ? mtv.w : (px * w0v.w + py * w1v.w + a3);
      *(float4*)&xs[p * LST + c0] = o;
    }
  }
  __syncthreads();

  const int dd = t & 15, ph = t >> 4;  // attention mappings

  // ---- transformer layers ----
  for (int li = 0; li < NDEPTH; ++li) {
    const float* Wqkv_i = a.Wqkv + li * NE * 3 * NE;
    const float* bqkv_i = a.bqkv + li * 3 * NE;
    const float* Wo_i   = a.Wo   + li * NE * NE;
    const float* bo_i   = a.bo   + li * NE;
    const float* Wm1_i  = a.Wm1  + li * NE * NMLP;
    const float* bm1_i  = a.bm1  + li * NMLP;
    const float* Wm2_i  = a.Wm2  + li * NMLP * NE;
    const float* bm2_i  = a.bm2  + li * NE;

    layer_norm(xs, hs, a.ln1s + li * NE, a.ln1b + li * NE, t, mrow, vrow);

    // attention, head by head (q,k,v 32x16 tiles in LDS)
    for (int hh = 0; hh < NHEADS; ++hh) {
      // qkv for this head: thread computes rows {ph, ph+16}, dim dd
      float aq0 = 0, aq1 = 0, ak0 = 0, ak1 = 0, av0 = 0, av1 = 0;
      const float* wcol = Wqkv_i + hh * NHD + dd;
#pragma unroll 4
      for (int k2 = 0; k2 < NE; ++k2) {
        const float* wr = wcol + k2 * (3 * NE);
        float wq = wr[0], wk = wr[NE], wv = wr[2 * NE];
        float h0 = hs[ph * LST + k2], h1 = hs[(ph + 16) * LST + k2];
        aq0 += h0 * wq; aq1 += h1 * wq;
        ak0 += h0 * wk; ak1 += h1 * wk;
        av0 += h0 * wv; av1 += h1 * wv;
      }
      {
        float bq = bqkv_i[hh * NHD + dd];
        float bk = bqkv_i[NE + hh * NHD + dd];
        float bv = bqkv_i[2 * NE + hh * NHD + dd];
        qs[ph * 17 + dd] = aq0 + bq;  qs[(ph + 16) * 17 + dd] = aq1 + bq;
        ks2[ph * 17 + dd] = ak0 + bk; ks2[(ph + 16) * 17 + dd] = ak1 + bk;
        vs[ph * 17 + dd] = av0 + bv;  vs[(ph + 16) * 17 + dd] = av1 + bv;
      }
      __syncthreads();
      // scores = 0.25 * q @ k^T
      {
        int pk = t & 31, pb = t >> 5;
#pragma unroll
        for (int ii = 0; ii < 4; ++ii) {
          int p = pb + 8 * ii;
          float acc = 0.f;
#pragma unroll
          for (int d2 = 0; d2 < NHD; ++d2) acc += qs[p * 17 + d2] * ks2[pk * 17 + d2];
          ss[p * 33 + pk] = 0.25f * acc;
        }
      }
      __syncthreads();
      // row softmax (store exp, srow = sum)
      {
        int p = t >> 3, j = t & 7;
        float v0 = ss[p * 33 + j * 4 + 0], v1 = ss[p * 33 + j * 4 + 1];
        float v2 = ss[p * 33 + j * 4 + 2], v3 = ss[p * 33 + j * 4 + 3];
        float mx = fmaxf(fmaxf(v0, v1), fmaxf(v2, v3));
#pragma unroll
        for (int o = 1; o < 8; o <<= 1) mx = fmaxf(mx, __shfl_xor(mx, o));
        v0 = expf(v0 - mx); v1 = expf(v1 - mx); v2 = expf(v2 - mx); v3 = expf(v3 - mx);
        float sm = v0 + v1 + v2 + v3;
#pragma unroll
        for (int o = 1; o < 8; o <<= 1) sm += __shfl_xor(sm, o);
        ss[p * 33 + j * 4 + 0] = v0; ss[p * 33 + j * 4 + 1] = v1;
        ss[p * 33 + j * 4 + 2] = v2; ss[p * 33 + j * 4 + 3] = v3;
        if (j == 0) srow[p] = sm;
      }
      __syncthreads();
      // o = (exp @ v) / srow  -> ts[:, hh*16 + dd]
      {
        float o0 = 0.f, o1 = 0.f;
#pragma unroll
        for (int pk = 0; pk < 32; ++pk) {
          float vv = vs[pk * 17 + dd];
          o0 += ss[ph * 33 + pk] * vv;
          o1 += ss[(ph + 16) * 33 + pk] * vv;
        }
        ts[ph * LST + hh * NHD + dd] = o0 / srow[ph];
        ts[(ph + 16) * LST + hh * NHD + dd] = o1 / srow[ph + 16];
      }
      __syncthreads();
    }

    // x += ts @ Wo + bo
    {
      float acc[4][4] = {};
      mm128(ts, Wo_i, NE, r0, c0, acc);
      float4 bv = *(const float4*)(bo_i + c0);
#pragma unroll
      for (int rr = 0; rr < 4; ++rr) {
        float4 v = *(float4*)&xs[(r0 + rr) * LST + c0];
        v.x += acc[rr][0] + bv.x; v.y += acc[rr][1] + bv.y;
        v.z += acc[rr][2] + bv.z; v.w += acc[rr][3] + bv.w;
        *(float4*)&xs[(r0 + rr) * LST + c0] = v;
      }
    }
    __syncthreads();

    layer_norm(xs, hs, a.ln2s + li * NE, a.ln2b + li * NE, t, mrow, vrow);

    // MLP: x += gelu(hs @ Wm1 + bm1) @ Wm2 + bm2   (chunked over 4x128 cols)
    {
      float acc2[4][4] = {};
      for (int ch = 0; ch < 4; ++ch) {
        float acc[4][4] = {};
        mm128(hs, Wm1_i, NMLP, r0, ch * 128 + c0, acc);
        float4 bv = *(const float4*)(bm1_i + ch * 128 + c0);
#pragma unroll
        for (int rr = 0; rr < 4; ++rr) {
          float4 o;
          o.x = gelu_f(acc[rr][0] + bv.x); o.y = gelu_f(acc[rr][1] + bv.y);
          o.z = gelu_f(acc[rr][2] + bv.z); o.w = gelu_f(acc[rr][3] + bv.w);
          *(float4*)&ts[(r0 + rr) * LST + c0] = o;
        }
        __syncthreads();
        mm128(ts, Wm2_i + ch * 128 * NE, NE, r0, c0, acc2);
        __syncthreads();
      }
      float4 bv = *(const float4*)(bm2_i + c0);
#pragma unroll
      for (int rr = 0; rr < 4; ++rr) {
        float4 v = *(float4*)&xs[(r0 + rr) * LST + c0];
        v.x += acc2[rr][0] + bv.x; v.y += acc2[rr][1] + bv.y;
        v.z += acc2[rr][2] + bv.z; v.w += acc2[rr][3] + bv.w;
        *(float4*)&xs[(r0 + rr) * LST + c0] = v;
      }
    }
    __syncthreads();
  }

  // ---- final LN + decoder ----
  layer_norm(xs, hs, a.lnfs, a.lnfb, t, mrow, vrow);

  float yacc = 0.f;
  const int pdec = t >> 1, ddec = t & 1;  // valid for t<64
  for (int ch = 0; ch < 4; ++ch) {
    {
      float acc[4][4] = {};
      mm128(hs, a.Wd1, NMLP, r0, ch * 128 + c0, acc);
      float4 bv = *(const float4*)(a.bd1 + ch * 128 + c0);
#pragma unroll
      for (int rr = 0; rr < 4; ++rr) {
        float4 o;
        o.x = fmaxf(acc[rr][0] + bv.x, 0.f); o.y = fmaxf(acc[rr][1] + bv.y, 0.f);
        o.z = fmaxf(acc[rr][2] + bv.z, 0.f); o.w = fmaxf(acc[rr][3] + bv.w, 0.f);
        *(float4*)&ts[(r0 + rr) * LST + c0] = o;
      }
    }
    __syncthreads();
    if (t < 64) {
#pragma unroll 4
      for (int k2 = 0; k2 < 128; ++k2)
        yacc += ts[pdec * LST + k2] * a.Wd2[(ch * 128 + k2) * 2 + ddec];
    }
    __syncthreads();
  }

  // ---- y write + loss partial ----
  if (t < 64) {
    float y = yacc + a.bd2[ddec];
    a.out[1 + (s * NP + pdec) * 2 + ddec] = y;
    float lnm = a.pos[(s * NP + pdec) * 2 + ddec] - (ddec ? cy : cx);
    float d = y - lnm;
    float part = (selv[pdec] != 0) ? d * d : 0.f;
#pragma unroll
    for (int o = 1; o < 64; o <<= 1) part += __shfl_xor(part, o);
    if (t == 0) {
      atomicAdd(a.wsf, part);
      int cnt = 0;
      for (int p = 0; p < NP; ++p) cnt += (selv[p] != 0) ? 1 : 0;
      atomicAdd(a.wsi, cnt);
    }
  }
}

__global__ void mrm_fin(const float* ws, float* out) {
  float num = ws[0];
  int cnt = ((const int*)ws)[1];
  float den = fmaxf((float)cnt * 2.0f, 1.0f);
  out[0] = num / den;
}

extern "C" void kernel_launch(void* const* d_in, const int* in_sizes, int n_in,
                              void* d_out, int out_size, void* d_ws, size_t ws_size,
                              hipStream_t stream) {
  (void)in_sizes; (void)n_in; (void)out_size; (void)ws_size;
  Args a;
  a.pos   = (const float*)d_in[0];
  a.ctr   = (const float*)d_in[1];
  a.ang   = (const float*)d_in[2];
  // d_in[3] = lane_padding_mask: unused (folded into sel_mask)
  a.sel   = (const int*)d_in[4];
  a.Wp    = (const float*)d_in[5];
  a.bp    = (const float*)d_in[6];
  a.Wpe1  = (const float*)d_in[7];
  a.bpe1  = (const float*)d_in[8];
  a.Wpe2  = (const float*)d_in[9];
  a.bpe2  = (const float*)d_in[10];
  a.ltype = (const float*)d_in[11];
  a.mtok  = (const float*)d_in[12];
  a.Wqkv  = (const float*)d_in[13];
  a.bqkv  = (const float*)d_in[14];
  a.Wo    = (const float*)d_in[15];
  a.bo    = (const float*)d_in[16];
  a.ln1s  = (const float*)d_in[17];
  a.ln1b  = (const float*)d_in[18];
  a.Wm1   = (const float*)d_in[19];
  a.bm1   = (const float*)d_in[20];
  a.Wm2   = (const float*)d_in[21];
  a.bm2   = (const float*)d_in[22];
  a.ln2s  = (const float*)d_in[23];
  a.ln2b  = (const float*)d_in[24];
  a.lnfs  = (const float*)d_in[25];
  a.lnfb  = (const float*)d_in[26];
  a.Wd1   = (const float*)d_in[27];
  a.bd1   = (const float*)d_in[28];
  a.Wd2   = (const float*)d_in[29];
  a.bd2   = (const float*)d_in[30];
  a.out   = (float*)d_out;
  a.wsf   = (float*)d_ws;
  a.wsi   = ((int*)d_ws) + 1;

  hipMemsetAsync(d_ws, 0, 8, stream);
  mrm_main<<<dim3(NSEQ), dim3(256), 0, stream>>>(a);
  mrm_fin<<<dim3(1), dim3(1), 0, stream>>>((const float*)d_ws, (float*)d_out);
}

// Round 4
// 3164.066 us; speedup vs baseline: 5.9248x; 5.9248x over previous
//
#include <hip/hip_runtime.h>

// ============================================================================
// ModelMRM fused forward, round 4: MFMA (bf16) for the 5 big GEMMs.
// - pack_w: per-launch weight f32->bf16 conversion + MFMA B-fragment packing
//   into d_ws (coalesced 16B/lane loads in the main kernel).
// - mrm_main_mfma: 1 block (256 thr = 4 waves) per sequence. Residual f32 in
//   LDS; GEMM A-operands staged as bf16 LDS tiles; attention f32 VALU with
//   in-register scores/softmax (8 heads x 32 rows = 256 threads).
// - Fallback to the round-3 VALU kernel if ws_size is too small.
// ============================================================================

#define NP 32
#define NE 128
#define NSEQ (64 * 256)
#define NHEADS 8
#define NHD 16
#define NMLP 512
#define NDEPTH 4
#define LST 132     // f32 LDS row stride
#define HBS 136     // bf16 LDS row stride (E=128 tiles)
#define H1S 520     // bf16 LDS row stride (MLP=512 tiles)

// packed-weight element offsets inside ws (u16 units, after 64B header)
#define QKV_W_OFF 0
#define O_W_OFF   196608
#define M1_W_OFF  262144
#define M2_W_OFF  524288
#define D1_W_OFF  786432
#define W_TOTAL   851968
#define WS_NEED   (64 + (size_t)W_TOTAL * 2)

typedef unsigned short u16;
typedef unsigned int u32;
typedef __attribute__((ext_vector_type(8))) short bf16x8;
typedef __attribute__((ext_vector_type(4))) float f32x4;
#define MFMA16 __builtin_amdgcn_mfma_f32_16x16x32_bf16

__device__ __forceinline__ float b2f(u16 u) {
  union { u32 i; float f; } v; v.i = ((u32)u) << 16; return v.f;
}
__device__ __forceinline__ u16 f2b(float f) {  // RNE f32 -> bf16
  union { float f; u32 i; } v; v.f = f;
  u32 x = v.i;
  x += 0x7fffu + ((x >> 16) & 1u);
  return (u16)(x >> 16);
}
__device__ __forceinline__ float gelu_f(float x) {
  return 0.5f * x * (1.0f + erff(x * 0.7071067811865475f));
}

struct Args {
  const float *pos, *ctr, *ang;
  const int *sel;
  const float *Wp, *bp, *Wpe1, *bpe1, *Wpe2, *bpe2, *ltype, *mtok;
  const float *Wqkv, *bqkv, *Wo, *bo, *ln1s, *ln1b, *Wm1, *bm1, *Wm2, *bm2;
  const float *ln2s, *ln2b, *lnfs, *lnfb, *Wd1, *bd1, *Wd2, *bd2;
  float* out;
  float* wsf;
  int* wsi;
};

// ---------------------------------------------------------------------------
// Weight pack: W[l][k][n] f32 -> bf16 fragments. dst element
// (((l*NT+nt)*KT+kt)*64 + lane)*8 + j  holds  W[l][kt*32+(lane>>4)*8+j][nt*16+(lane&15)]
// ---------------------------------------------------------------------------
__global__ void pack_w(const float* __restrict__ src, u16* __restrict__ dst,
                       int K, int N, int L) {
  int id = blockIdx.x * 256 + threadIdx.x;
  int KT = K >> 5, NT = N >> 4;
  int total = L * NT * KT * 64;
  if (id >= total) return;
  int lane = id & 63;
  int rest = id >> 6;
  int kt = rest % KT;
  int rest2 = rest / KT;
  int nt = rest2 % NT;
  int l = rest2 / NT;
  const float* s = src + (size_t)l * K * N + (size_t)(kt * 32 + (lane >> 4) * 8) * N
                 + nt * 16 + (lane & 15);
  u16 tmp[8];
#pragma unroll
  for (int j = 0; j < 8; ++j) tmp[j] = f2b(s[(size_t)j * N]);
  ((uint4*)dst)[id] = *(const uint4*)tmp;
}

// ---------------------------------------------------------------------------
// GEMM helpers: wave computes 32 x (NTW*16) slab, K=128 (KT=4), A bf16 in LDS.
// C layout per mfma: row = (lane>>4)*4 + j (+16 for acc[1]), col = lane&15.
// ---------------------------------------------------------------------------
template <int NTW>
__device__ __forceinline__ void gemm_kt4(const u16* __restrict__ hA, int SA,
                                         const u16* __restrict__ B, int w,
                                         int lane, f32x4 (&acc)[NTW][2]) {
  int ar = lane & 15, ac = (lane >> 4) * 8;
  bf16x8 af[8];
#pragma unroll
  for (int kb = 0; kb < 4; ++kb) {
    af[kb]     = *(const bf16x8*)(hA + ar * SA + kb * 32 + ac);
    af[kb + 4] = *(const bf16x8*)(hA + (ar + 16) * SA + kb * 32 + ac);
  }
#pragma unroll
  for (int i = 0; i < NTW; ++i) {
    int nt = w + 4 * i;
    const u16* Bp = B + (size_t)nt * 2048 + lane * 8;
    f32x4 z = {0.f, 0.f, 0.f, 0.f};
    acc[i][0] = z; acc[i][1] = z;
#pragma unroll
    for (int kb = 0; kb < 4; ++kb) {
      bf16x8 b = *(const bf16x8*)(Bp + kb * 512);
      acc[i][0] = MFMA16(af[kb], b, acc[i][0], 0, 0, 0);
      acc[i][1] = MFMA16(af[kb + 4], b, acc[i][1], 0, 0, 0);
    }
  }
}

// K=512 (KT=16), 2 ntiles per wave, A bf16 LDS stride H1S.
__device__ __forceinline__ void gemm_kt16_nt2(const u16* __restrict__ hA,
                                              const u16* __restrict__ B, int w,
                                              int lane, f32x4 (&acc)[2][2]) {
  int ar = lane & 15, ac = (lane >> 4) * 8;
  f32x4 z = {0.f, 0.f, 0.f, 0.f};
  acc[0][0] = z; acc[0][1] = z; acc[1][0] = z; acc[1][1] = z;
#pragma unroll
  for (int kc = 0; kc < 4; ++kc) {
    bf16x8 af[8];
#pragma unroll
    for (int k2 = 0; k2 < 4; ++k2) {
      int kb = kc * 4 + k2;
      af[k2]     = *(const bf16x8*)(hA + ar * H1S + kb * 32 + ac);
      af[k2 + 4] = *(const bf16x8*)(hA + (ar + 16) * H1S + kb * 32 + ac);
    }
#pragma unroll
    for (int i = 0; i < 2; ++i) {
      int nt = w + 4 * i;
      const u16* Bp = B + (size_t)nt * 8192 + (size_t)(kc * 4) * 512 + lane * 8;
#pragma unroll
      for (int k2 = 0; k2 < 4; ++k2) {
        bf16x8 b = *(const bf16x8*)(Bp + k2 * 512);
        acc[i][0] = MFMA16(af[k2], b, acc[i][0], 0, 0, 0);
        acc[i][1] = MFMA16(af[k2 + 4], b, acc[i][1], 0, 0, 0);
      }
    }
  }
}

// LN(src f32 [32][LST]) * gam + bet -> dst bf16 [32][HBS]
__device__ __forceinline__ void layer_norm_bf(const float* __restrict__ src,
                                              u16* __restrict__ dst,
                                              const float* gam, const float* bet,
                                              int t, float* mrow, float* vrow) {
  int p = t >> 3, j0 = (t & 7) * 16;
  const float* row = src + p * LST + j0;
  float sum = 0.f, sq = 0.f;
#pragma unroll
  for (int k = 0; k < 16; ++k) { float v = row[k]; sum += v; sq += v * v; }
#pragma unroll
  for (int o = 1; o < 8; o <<= 1) { sum += __shfl_xor(sum, o); sq += __shfl_xor(sq, o); }
  if ((t & 7) == 0) {
    float m = sum * 0.0078125f;
    mrow[p] = m;
    vrow[p] = sq * 0.0078125f - m * m;
  }
  __syncthreads();
  float m = mrow[p], rs = rsqrtf(vrow[p] + 1e-5f);
  u32 wb[8];
#pragma unroll
  for (int k8 = 0; k8 < 4; ++k8) {
    float4 v = ((const float4*)row)[k8];
    float4 g = ((const float4*)(gam + j0))[k8];
    float4 b = ((const float4*)(bet + j0))[k8];
    wb[k8 * 2]     = (u32)f2b((v.x - m) * rs * g.x + b.x) | ((u32)f2b((v.y - m) * rs * g.y + b.y) << 16);
    wb[k8 * 2 + 1] = (u32)f2b((v.z - m) * rs * g.z + b.z) | ((u32)f2b((v.w - m) * rs * g.w + b.w) << 16);
  }
  uint4* dp = (uint4*)(dst + p * HBS + j0);
  dp[0] = make_uint4(wb[0], wb[1], wb[2], wb[3]);
  dp[1] = make_uint4(wb[4], wb[5], wb[6], wb[7]);
  __syncthreads();
}

__global__ __launch_bounds__(256, 2) void mrm_main_mfma(Args a, const u16* __restrict__ wsW) {
  __shared__ float xs[32 * LST];       // residual, f32
  __shared__ u16 hbf[32 * HBS];        // bf16 A-tiles (E=128)
  __shared__ float uni[12672];         // union: {q,k,v f32} | {h1bf bf16 + wd2s}
  __shared__ float tvec[128], pvec[128], mrow[32], vrow[32];
  __shared__ int selv[32];
  __shared__ float lacc;

  float* qsh = uni;
  float* ksh = uni + 4224;
  float* vsh = uni + 8448;
  u16* h1bf = (u16*)uni;               // 32*520 u16 = 8320 f32
  float* wd2s = uni + 8320;            // 1024 f32

  const int s = blockIdx.x;
  const int t = threadIdx.x;
  const int w = t >> 6, lane = t & 63;
  const int cr = lane & 15, rq = (lane >> 4) * 4;
  const int rg = t >> 5, cg = t & 31, r0 = rg * 4, c0 = cg * 4;

  if (t == 0) lacc = 0.f;
  if (t < 32) selv[t] = a.sel[s * NP + t];

  const float cx = a.ctr[s * 2 + 0];
  const float cy = a.ctr[s * 2 + 1];
  const float an = a.ang[s];
  const float ca = cosf(an), sa = sinf(an);

  // ---- positional embedding (VALU, tiny) ----
  if (t < 128) {
    float accp = a.bpe1[t] + cx * a.Wpe1[t] + cy * a.Wpe1[128 + t]
               + ca * a.Wpe1[256 + t] + sa * a.Wpe1[384 + t];
    tvec[t] = gelu_f(accp);
  }
  __syncthreads();
  if (t < 128) {
    float accp = a.bpe2[t];
    for (int e = 0; e < 128; ++e) accp += tvec[e] * a.Wpe2[e * 128 + t];
    pvec[t] = accp;
  }
  __syncthreads();

  // ---- token build -> xs f32 ----
  {
    float4 w0v = *(const float4*)(a.Wp + c0);
    float4 w1v = *(const float4*)(a.Wp + NE + c0);
    float4 bpv = *(const float4*)(a.bp + c0);
    float4 ltv = *(const float4*)(a.ltype + c0);
    float4 mtv = *(const float4*)(a.mtok + c0);
    float a0 = bpv.x + pvec[c0 + 0] + ltv.x;
    float a1 = bpv.y + pvec[c0 + 1] + ltv.y;
    float a2 = bpv.z + pvec[c0 + 2] + ltv.z;
    float a3 = bpv.w + pvec[c0 + 3] + ltv.w;
#pragma unroll
    for (int rr = 0; rr < 4; ++rr) {
      int p = r0 + rr;
      float px = a.pos[(s * NP + p) * 2 + 0] - cx;
      float py = a.pos[(s * NP + p) * 2 + 1] - cy;
      bool mk = selv[p] != 0;
      float4 o;
      o.x = mk ? mtv.x : (px * w0v.x + py * w1v.x + a0);
      o.y = mk ? mtv.y : (px * w0v.y + py * w1v.y + a1);
      o.z = mk ? mtv.z : (px * w0v.z + py * w1v.z + a2);
      o.w = mk ? mtv.w : (px * w0v.w + py * w1v.w + a3);
      *(float4*)&xs[p * LST + c0] = o;
    }
  }
  __syncthreads();

  const int hh = t >> 5, pp = t & 31;  // attention mapping

  // ---- layers ----
  for (int li = 0; li < NDEPTH; ++li) {
    const u16* qkvW = wsW + QKV_W_OFF + li * 49152;
    const u16* oW   = wsW + O_W_OFF   + li * 16384;
    const u16* m1W  = wsW + M1_W_OFF  + li * 65536;
    const u16* m2W  = wsW + M2_W_OFF  + li * 65536;
    const float* bqkv_i = a.bqkv + li * 384;
    const float* bo_i   = a.bo + li * NE;
    const float* bm1_i  = a.bm1 + li * NMLP;
    const float* bm2_i  = a.bm2 + li * NE;

    layer_norm_bf(xs, hbf, a.ln1s + li * NE, a.ln1b + li * NE, t, mrow, vrow);

    // ---- QKV: [32x128]bf16 @ [128x384] -> q/k/v f32 LDS ----
    {
      f32x4 acc[6][2];
      gemm_kt4<6>(hbf, HBS, qkvW, w, lane, acc);
#pragma unroll
      for (int i = 0; i < 6; ++i) {
        int nt = w + 4 * i;
        int n = nt * 16 + cr;
        float bias = bqkv_i[n];
        float* dst = (n < 128) ? qsh : (n < 256) ? ksh : vsh;
        int nn = n & 127;
#pragma unroll
        for (int j = 0; j < 4; ++j) {
          dst[(rq + j) * LST + nn]      = acc[i][0][j] + bias;
          dst[(rq + j + 16) * LST + nn] = acc[i][1][j] + bias;
        }
      }
    }
    __syncthreads();

    // ---- attention: thread = (head hh, row pp); scores/softmax in regs ----
    {
      const float* qr = qsh + pp * LST + hh * 16;
      float4 q0 = ((const float4*)qr)[0], q1 = ((const float4*)qr)[1];
      float4 q2 = ((const float4*)qr)[2], q3 = ((const float4*)qr)[3];
      float sc[32];
#pragma unroll
      for (int j = 0; j < 32; ++j) {
        const float* kr = ksh + j * LST + hh * 16;
        float4 k0 = ((const float4*)kr)[0], k1 = ((const float4*)kr)[1];
        float4 k2 = ((const float4*)kr)[2], k3 = ((const float4*)kr)[3];
        sc[j] = 0.25f * (q0.x*k0.x + q0.y*k0.y + q0.z*k0.z + q0.w*k0.w
                       + q1.x*k1.x + q1.y*k1.y + q1.z*k1.z + q1.w*k1.w
                       + q2.x*k2.x + q2.y*k2.y + q2.z*k2.z + q2.w*k2.w
                       + q3.x*k3.x + q3.y*k3.y + q3.z*k3.z + q3.w*k3.w);
      }
      float mx = sc[0];
#pragma unroll
      for (int j = 1; j < 32; ++j) mx = fmaxf(mx, sc[j]);
      float sum = 0.f;
#pragma unroll
      for (int j = 0; j < 32; ++j) { sc[j] = __expf(sc[j] - mx); sum += sc[j]; }
      float inv = 1.f / sum;
      float4 o0 = {0,0,0,0}, o1 = {0,0,0,0}, o2 = {0,0,0,0}, o3 = {0,0,0,0};
#pragma unroll
      for (int j = 0; j < 32; ++j) {
        const float* vr = vsh + j * LST + hh * 16;
        float4 v0 = ((const float4*)vr)[0], v1 = ((const float4*)vr)[1];
        float4 v2 = ((const float4*)vr)[2], v3 = ((const float4*)vr)[3];
        float pj = sc[j];
        o0.x += pj*v0.x; o0.y += pj*v0.y; o0.z += pj*v0.z; o0.w += pj*v0.w;
        o1.x += pj*v1.x; o1.y += pj*v1.y; o1.z += pj*v1.z; o1.w += pj*v1.w;
        o2.x += pj*v2.x; o2.y += pj*v2.y; o2.z += pj*v2.z; o2.w += pj*v2.w;
        o3.x += pj*v3.x; o3.y += pj*v3.y; o3.z += pj*v3.z; o3.w += pj*v3.w;
      }
      u32 wb[8];
      wb[0] = (u32)f2b(o0.x*inv) | ((u32)f2b(o0.y*inv) << 16);
      wb[1] = (u32)f2b(o0.z*inv) | ((u32)f2b(o0.w*inv) << 16);
      wb[2] = (u32)f2b(o1.x*inv) | ((u32)f2b(o1.y*inv) << 16);
      wb[3] = (u32)f2b(o1.z*inv) | ((u32)f2b(o1.w*inv) << 16);
      wb[4] = (u32)f2b(o2.x*inv) | ((u32)f2b(o2.y*inv) << 16);
      wb[5] = (u32)f2b(o2.z*inv) | ((u32)f2b(o2.w*inv) << 16);
      wb[6] = (u32)f2b(o3.x*inv) | ((u32)f2b(o3.y*inv) << 16);
      wb[7] = (u32)f2b(o3.z*inv) | ((u32)f2b(o3.w*inv) << 16);
      uint4* dp = (uint4*)(hbf + pp * HBS + hh * 16);
      dp[0] = make_uint4(wb[0], wb[1], wb[2], wb[3]);
      dp[1] = make_uint4(wb[4], wb[5], wb[6], wb[7]);
    }
    __syncthreads();

    // ---- proj: attn_out(bf16) @ Wo -> xs += ----
    {
      f32x4 acc[2][2];
      gemm_kt4<2>(hbf, HBS, oW, w, lane, acc);
#pragma unroll
      for (int i = 0; i < 2; ++i) {
        int n = (w + 4 * i) * 16 + cr;
        float bias = bo_i[n];
#pragma unroll
        for (int j = 0; j < 4; ++j) {
          xs[(rq + j) * LST + n]      += acc[i][0][j] + bias;
          xs[(rq + j + 16) * LST + n] += acc[i][1][j] + bias;
        }
      }
    }
    __syncthreads();

    layer_norm_bf(xs, hbf, a.ln2s + li * NE, a.ln2b + li * NE, t, mrow, vrow);

    // ---- MLP1: hbf @ Wm1 -> gelu -> h1bf ----
    {
      f32x4 acc[8][2];
      gemm_kt4<8>(hbf, HBS, m1W, w, lane, acc);
#pragma unroll
      for (int i = 0; i < 8; ++i) {
        int n = (w + 4 * i) * 16 + cr;
        float bias = bm1_i[n];
#pragma unroll
        for (int j = 0; j < 4; ++j) {
          h1bf[(rq + j) * H1S + n]      = f2b(gelu_f(acc[i][0][j] + bias));
          h1bf[(rq + j + 16) * H1S + n] = f2b(gelu_f(acc[i][1][j] + bias));
        }
      }
    }
    __syncthreads();

    // ---- MLP2: h1bf @ Wm2 -> xs += ----
    {
      f32x4 acc[2][2];
      gemm_kt16_nt2(h1bf, m2W, w, lane, acc);
#pragma unroll
      for (int i = 0; i < 2; ++i) {
        int n = (w + 4 * i) * 16 + cr;
        float bias = bm2_i[n];
#pragma unroll
        for (int j = 0; j < 4; ++j) {
          xs[(rq + j) * LST + n]      += acc[i][0][j] + bias;
          xs[(rq + j + 16) * LST + n] += acc[i][1][j] + bias;
        }
      }
    }
    __syncthreads();
  }

  // ---- final LN -> hbf ----
  layer_norm_bf(xs, hbf, a.lnfs, a.lnfb, t, mrow, vrow);

  // preload Wd2 (f32) into LDS (region disjoint from h1bf)
  for (int i = t; i < 1024; i += 256) wd2s[i] = a.Wd2[i];

  // ---- dec1: hbf @ Wd1 -> relu -> h1bf ----
  {
    f32x4 acc[8][2];
    gemm_kt4<8>(hbf, HBS, wsW + D1_W_OFF, w, lane, acc);
#pragma unroll
    for (int i = 0; i < 8; ++i) {
      int n = (w + 4 * i) * 16 + cr;
      float bias = a.bd1[n];
#pragma unroll
      for (int j = 0; j < 4; ++j) {
        h1bf[(rq + j) * H1S + n]      = f2b(fmaxf(acc[i][0][j] + bias, 0.f));
        h1bf[(rq + j + 16) * H1S + n] = f2b(fmaxf(acc[i][1][j] + bias, 0.f));
      }
    }
  }
  __syncthreads();

  // ---- dec2 + y write + loss: 4 threads per output ----
  {
    int p = t >> 3;
    int dd = (t >> 2) & 1;
    int q4 = t & 3;
    const u16* hrow = h1bf + p * H1S + q4 * 128;
    const float* wrow = wd2s + q4 * 256 + dd;
    float acc = 0.f;
#pragma unroll 8
    for (int k = 0; k < 128; ++k) acc += b2f(hrow[k]) * wrow[k * 2];
    acc += __shfl_xor(acc, 1);
    acc += __shfl_xor(acc, 2);
    if (q4 == 0) {
      float y = acc + a.bd2[dd];
      a.out[1 + (s * NP + p) * 2 + dd] = y;
      float lnm = a.pos[(s * NP + p) * 2 + dd] - (dd ? cy : cx);
      float d = y - lnm;
      if (selv[p] != 0) atomicAdd(&lacc, d * d);
    }
  }
  __syncthreads();
  if (t == 0) {
    atomicAdd(a.wsf, lacc);
    int cnt = 0;
#pragma unroll
    for (int p = 0; p < NP; ++p) cnt += (selv[p] != 0) ? 1 : 0;
    atomicAdd(a.wsi, cnt);
  }
}

// ============================================================================
// Round-3 VALU fallback (used only if ws_size < WS_NEED)
// ============================================================================
__device__ __forceinline__ void mm128(const float* __restrict__ src,
                                      const float* __restrict__ W, int ldw,
                                      int r0, int cabs, float acc[4][4]) {
#pragma unroll 4
  for (int k = 0; k < NE; ++k) {
    float4 wv = *(const float4*)(W + k * ldw + cabs);
#pragma unroll
    for (int rr = 0; rr < 4; ++rr) {
      float sv = src[(r0 + rr) * LST + k];
      acc[rr][0] += sv * wv.x; acc[rr][1] += sv * wv.y;
      acc[rr][2] += sv * wv.z; acc[rr][3] += sv * wv.w;
    }
  }
}

__device__ __forceinline__ void layer_norm(const float* __restrict__ src,
                                           float* __restrict__ dst,
                                           const float* gam, const float* bet,
                                           int t, float* mrow, float* vrow) {
  {
    int p = t >> 3, j = t & 7;
    const float* row = src + p * LST + j * 16;
    float sum = 0.f, sq = 0.f;
#pragma unroll
    for (int k2 = 0; k2 < 16; ++k2) { float v = row[k2]; sum += v; sq += v * v; }
#pragma unroll
    for (int o = 1; o < 8; o <<= 1) { sum += __shfl_xor(sum, o); sq += __shfl_xor(sq, o); }
    if (j == 0) {
      float m = sum * 0.0078125f;
      mrow[p] = m;
      vrow[p] = sq * 0.0078125f - m * m;
    }
  }
  __syncthreads();
  {
    int rg = t >> 5, cg = t & 31, r0 = rg * 4, c0 = cg * 4;
    float4 gv = *(const float4*)(gam + c0);
    float4 bv = *(const float4*)(bet + c0);
#pragma unroll
    for (int rr = 0; rr < 4; ++rr) {
      int r = r0 + rr;
      float m = mrow[r], rs = rsqrtf(vrow[r] + 1e-5f);
      float4 v = *(const float4*)&src[r * LST + c0];
      float4 o;
      o.x = (v.x - m) * rs * gv.x + bv.x;
      o.y = (v.y - m) * rs * gv.y + bv.y;
      o.z = (v.z - m) * rs * gv.z + bv.z;
      o.w = (v.w - m) * rs * gv.w + bv.w;
      *(float4*)&dst[r * LST + c0] = o;
    }
  }
  __syncthreads();
}

__global__ __launch_bounds__(256, 2) void mrm_main_valu(Args a) {
  __shared__ float xs[32 * LST];
  __shared__ float hs[32 * LST];
  __shared__ float ts[32 * LST];
  __shared__ float qs[32 * 17];
  __shared__ float ks2[32 * 17];
  __shared__ float vs[32 * 17];
  __shared__ float ss[32 * 33];
  __shared__ float tvec[128];
  __shared__ float pvec[128];
  __shared__ float mrow[32], vrow[32], srow[32];
  __shared__ int selv[32];

  const int s = blockIdx.x;
  const int t = threadIdx.x;
  const int rg = t >> 5, cg = t & 31, r0 = rg * 4, c0 = cg * 4;

  if (t < 32) selv[t] = a.sel[s * NP + t];

  const float cx = a.ctr[s * 2 + 0];
  const float cy = a.ctr[s * 2 + 1];
  const float an = a.ang[s];
  const float ca = cosf(an), sa = sinf(an);

  if (t < 128) {
    float accp = a.bpe1[t] + cx * a.Wpe1[t] + cy * a.Wpe1[128 + t]
               + ca * a.Wpe1[256 + t] + sa * a.Wpe1[384 + t];
    tvec[t] = gelu_f(accp);
  }
  __syncthreads();
  if (t < 128) {
    float accp = a.bpe2[t];
    for (int e = 0; e < 128; ++e) accp += tvec[e] * a.Wpe2[e * 128 + t];
    pvec[t] = accp;
  }
  __syncthreads();

  {
    float4 w0v = *(const float4*)(a.Wp + c0);
    float4 w1v = *(const float4*)(a.Wp + NE + c0);
    float4 bpv = *(const float4*)(a.bp + c0);
    float4 ltv = *(const float4*)(a.ltype + c0);
    float4 mtv = *(const float4*)(a.mtok + c0);
    float a0 = bpv.x + pvec[c0 + 0] + ltv.x;
    float a1 = bpv.y + pvec[c0 + 1] + ltv.y;
    float a2 = bpv.z + pvec[c0 + 2] + ltv.z;
    float a3 = bpv.w + pvec[c0 + 3] + ltv.w;
#pragma unroll
    for (int rr = 0; rr < 4; ++rr) {
      int p = r0 + rr;
      float px = a.pos[(s * NP + p) * 2 + 0] - cx;
      float py = a.pos[(s * NP + p) * 2 + 1] - cy;
      bool mk = selv[p] != 0;
      float4 o;
      o.x = mk ? mtv.x : (px * w0v.x + py * w1v.x + a0);
      o.y = mk ? mtv.y : (px * w0v.y + py * w1v.y + a1);
      o.z = mk ? mtv.z : (px * w0v.z + py * w1v.z + a2);
      o.w = mk ? mtv.w : (px * w0v.w + py * w1v.w + a3);
      *(float4*)&xs[p * LST + c0] = o;
    }
  }
  __syncthreads();

  const int dd = t & 15, ph = t >> 4;

  for (int li = 0; li < NDEPTH; ++li) {
    const float* Wqkv_i = a.Wqkv + li * NE * 3 * NE;
    const float* bqkv_i = a.bqkv + li * 3 * NE;
    const float* Wo_i   = a.Wo   + li * NE * NE;
    const float* bo_i   = a.bo   + li * NE;
    const float* Wm1_i  = a.Wm1  + li * NE * NMLP;
    const float* bm1_i  = a.bm1  + li * NMLP;
    const float* Wm2_i  = a.Wm2  + li * NMLP * NE;
    const float* bm2_i  = a.bm2  + li * NE;

    layer_norm(xs, hs, a.ln1s + li * NE, a.ln1b + li * NE, t, mrow, vrow);

    for (int hh = 0; hh < NHEADS; ++hh) {
      float aq0 = 0, aq1 = 0, ak0 = 0, ak1 = 0, av0 = 0, av1 = 0;
      const float* wcol = Wqkv_i + hh * NHD + dd;
#pragma unroll 4
      for (int k2 = 0; k2 < NE; ++k2) {
        const float* wr = wcol + k2 * (3 * NE);
        float wq = wr[0], wk = wr[NE], wv = wr[2 * NE];
        float h0 = hs[ph * LST + k2], h1 = hs[(ph + 16) * LST + k2];
        aq0 += h0 * wq; aq1 += h1 * wq;
        ak0 += h0 * wk; ak1 += h1 * wk;
        av0 += h0 * wv; av1 += h1 * wv;
      }
      {
        float bq = bqkv_i[hh * NHD + dd];
        float bk = bqkv_i[NE + hh * NHD + dd];
        float bv = bqkv_i[2 * NE + hh * NHD + dd];
        qs[ph * 17 + dd] = aq0 + bq;  qs[(ph + 16) * 17 + dd] = aq1 + bq;
        ks2[ph * 17 + dd] = ak0 + bk; ks2[(ph + 16) * 17 + dd] = ak1 + bk;
        vs[ph * 17 + dd] = av0 + bv;  vs[(ph + 16) * 17 + dd] = av1 + bv;
      }
      __syncthreads();
      {
        int pk = t & 31, pb = t >> 5;
#pragma unroll
        for (int ii = 0; ii < 4; ++ii) {
          int p = pb + 8 * ii;
          float acc = 0.f;
#pragma unroll
          for (int d2 = 0; d2 < NHD; ++d2) acc += qs[p * 17 + d2] * ks2[pk * 17 + d2];
          ss[p * 33 + pk] = 0.25f * acc;
        }
      }
      __syncthreads();
      {
        int p = t >> 3, j = t & 7;
        float v0 = ss[p * 33 + j * 4 + 0], v1 = ss[p * 33 + j * 4 + 1];
        float v2 = ss[p * 33 + j * 4 + 2], v3 = ss[p * 33 + j * 4 + 3];
        float mx = fmaxf(fmaxf(v0, v1), fmaxf(v2, v3));
#pragma unroll
        for (int o = 1; o < 8; o <<= 1) mx = fmaxf(mx, __shfl_xor(mx, o));
        v0 = expf(v0 - mx); v1 = expf(v1 - mx); v2 = expf(v2 - mx); v3 = expf(v3 - mx);
        float sm = v0 + v1 + v2 + v3;
#pragma unroll
        for (int o = 1; o < 8; o <<= 1) sm += __shfl_xor(sm, o);
        ss[p * 33 + j * 4 + 0] = v0; ss[p * 33 + j * 4 + 1] = v1;
        ss[p * 33 + j * 4 + 2] = v2; ss[p * 33 + j * 4 + 3] = v3;
        if (j == 0) srow[p] = sm;
      }
      __syncthreads();
      {
        float o0 = 0.f, o1 = 0.f;
#pragma unroll
        for (int pk = 0; pk < 32; ++pk) {
          float vv = vs[pk * 17 + dd];
          o0 += ss[ph * 33 + pk] * vv;
          o1 += ss[(ph + 16) * 33 + pk] * vv;
        }
        ts[ph * LST + hh * NHD + dd] = o0 / srow[ph];
        ts[(ph + 16) * LST + hh * NHD + dd] = o1 / srow[ph + 16];
      }
      __syncthreads();
    }

    {
      float acc[4][4] = {};
      mm128(ts, Wo_i, NE, r0, c0, acc);
      float4 bv = *(const float4*)(bo_i + c0);
#pragma unroll
      for (int rr = 0; rr < 4; ++rr) {
        float4 v = *(float4*)&xs[(r0 + rr) * LST + c0];
        v.x += acc[rr][0] + bv.x; v.y += acc[rr][1] + bv.y;
        v.z += acc[rr][2] + bv.z; v.w += acc[rr][3] + bv.w;
        *(float4*)&xs[(r0 + rr) * LST + c0] = v;
      }
    }
    __syncthreads();

    layer_norm(xs, hs, a.ln2s + li * NE, a.ln2b + li * NE, t, mrow, vrow);

    {
      float acc2[4][4] = {};
      for (int ch = 0; ch < 4; ++ch) {
        float acc[4][4] = {};
        mm128(hs, Wm1_i, NMLP, r0, ch * 128 + c0, acc);
        float4 bv = *(const float4*)(bm1_i + ch * 128 + c0);
#pragma unroll
        for (int rr = 0; rr < 4; ++rr) {
          float4 o;
          o.x = gelu_f(acc[rr][0] + bv.x); o.y = gelu_f(acc[rr][1] + bv.y);
          o.z = gelu_f(acc[rr][2] + bv.z); o.w = gelu_f(acc[rr][3] + bv.w);
          *(float4*)&ts[(r0 + rr) * LST + c0] = o;
        }
        __syncthreads();
        mm128(ts, Wm2_i + ch * 128 * NE, NE, r0, c0, acc2);
        __syncthreads();
      }
      float4 bv = *(const float4*)(bm2_i + c0);
#pragma unroll
      for (int rr = 0; rr < 4; ++rr) {
        float4 v = *(float4*)&xs[(r0 + rr) * LST + c0];
        v.x += acc2[rr][0] + bv.x; v.y += acc2[rr][1] + bv.y;
        v.z += acc2[rr][2] + bv.z; v.w += acc2[rr][3] + bv.w;
        *(float4*)&xs[(r0 + rr) * LST + c0] = v;
      }
    }
    __syncthreads();
  }

  layer_norm(xs, hs, a.lnfs, a.lnfb, t, mrow, vrow);

  float yacc = 0.f;
  const int pdec = t >> 1, ddec = t & 1;
  for (int ch = 0; ch < 4; ++ch) {
    {
      float acc[4][4] = {};
      mm128(hs, a.Wd1, NMLP, r0, ch * 128 + c0, acc);
      float4 bv = *(const float4*)(a.bd1 + ch * 128 + c0);
#pragma unroll
      for (int rr = 0; rr < 4; ++rr) {
        float4 o;
        o.x = fmaxf(acc[rr][0] + bv.x, 0.f); o.y = fmaxf(acc[rr][1] + bv.y, 0.f);
        o.z = fmaxf(acc[rr][2] + bv.z, 0.f); o.w = fmaxf(acc[rr][3] + bv.w, 0.f);
        *(float4*)&ts[(r0 + rr) * LST + c0] = o;
      }
    }
    __syncthreads();
    if (t < 64) {
#pragma unroll 4
      for (int k2 = 0; k2 < 128; ++k2)
        yacc += ts[pdec * LST + k2] * a.Wd2[(ch * 128 + k2) * 2 + ddec];
    }
    __syncthreads();
  }

  if (t < 64) {
    float y = yacc + a.bd2[ddec];
    a.out[1 + (s * NP + pdec) * 2 + ddec] = y;
    float lnm = a.pos[(s * NP + pdec) * 2 + ddec] - (ddec ? cy : cx);
    float d = y - lnm;
    float part = (selv[pdec] != 0) ? d * d : 0.f;
#pragma unroll
    for (int o = 1; o < 64; o <<= 1) part += __shfl_xor(part, o);
    if (t == 0) {
      atomicAdd(a.wsf, part);
      int cnt = 0;
      for (int p = 0; p < NP; ++p) cnt += (selv[p] != 0) ? 1 : 0;
      atomicAdd(a.wsi, cnt);
    }
  }
}

__global__ void mrm_fin(const float* ws, float* out) {
  float num = ws[0];
  int cnt = ((const int*)ws)[1];
  float den = fmaxf((float)cnt * 2.0f, 1.0f);
  out[0] = num / den;
}

extern "C" void kernel_launch(void* const* d_in, const int* in_sizes, int n_in,
                              void* d_out, int out_size, void* d_ws, size_t ws_size,
                              hipStream_t stream) {
  (void)in_sizes; (void)n_in; (void)out_size;
  Args a;
  a.pos   = (const float*)d_in[0];
  a.ctr   = (const float*)d_in[1];
  a.ang   = (const float*)d_in[2];
  a.sel   = (const int*)d_in[4];
  a.Wp    = (const float*)d_in[5];
  a.bp    = (const float*)d_in[6];
  a.Wpe1  = (const float*)d_in[7];
  a.bpe1  = (const float*)d_in[8];
  a.Wpe2  = (const float*)d_in[9];
  a.bpe2  = (const float*)d_in[10];
  a.ltype = (const float*)d_in[11];
  a.mtok  = (const float*)d_in[12];
  a.Wqkv  = (const float*)d_in[13];
  a.bqkv  = (const float*)d_in[14];
  a.Wo    = (const float*)d_in[15];
  a.bo    = (const float*)d_in[16];
  a.ln1s  = (const float*)d_in[17];
  a.ln1b  = (const float*)d_in[18];
  a.Wm1   = (const float*)d_in[19];
  a.bm1   = (const float*)d_in[20];
  a.Wm2   = (const float*)d_in[21];
  a.bm2   = (const float*)d_in[22];
  a.ln2s  = (const float*)d_in[23];
  a.ln2b  = (const float*)d_in[24];
  a.lnfs  = (const float*)d_in[25];
  a.lnfb  = (const float*)d_in[26];
  a.Wd1   = (const float*)d_in[27];
  a.bd1   = (const float*)d_in[28];
  a.Wd2   = (const float*)d_in[29];
  a.bd2   = (const float*)d_in[30];
  a.out   = (float*)d_out;
  a.wsf   = (float*)d_ws;
  a.wsi   = ((int*)d_ws) + 1;

  hipMemsetAsync(d_ws, 0, 8, stream);
  if (ws_size >= WS_NEED) {
    u16* wsW = (u16*)((char*)d_ws + 64);
    pack_w<<<dim3(96),  dim3(256), 0, stream>>>(a.Wqkv, wsW + QKV_W_OFF, 128, 384, 4);
    pack_w<<<dim3(32),  dim3(256), 0, stream>>>(a.Wo,   wsW + O_W_OFF,   128, 128, 4);
    pack_w<<<dim3(128), dim3(256), 0, stream>>>(a.Wm1,  wsW + M1_W_OFF,  128, 512, 4);
    pack_w<<<dim3(128), dim3(256), 0, stream>>>(a.Wm2,  wsW + M2_W_OFF,  512, 128, 4);
    pack_w<<<dim3(32),  dim3(256), 0, stream>>>(a.Wd1,  wsW + D1_W_OFF,  128, 512, 1);
    mrm_main_mfma<<<dim3(NSEQ), dim3(256), 0, stream>>>(a, wsW);
  } else {
    mrm_main_valu<<<dim3(NSEQ), dim3(256), 0, stream>>>(a);
  }
  mrm_fin<<<dim3(1), dim3(1), 0, stream>>>((const float*)d_ws, (float*)d_out);
}

// Round 5
// 2473.313 us; speedup vs baseline: 7.5796x; 1.2793x over previous
//
#include <hip/hip_runtime.h>

// ============================================================================
// ModelMRM fused forward, round 5: MFMA everywhere (GEMMs + attention).
// - QK^T: mfma_16x16x32_bf16 with zero-padded K (d=16 real); S^T layout so
//   softmax is lane-local + 2 shfl_xor. P A-frag for PV built via ds_bpermute.
// - Q/K/V bf16 LDS tiles (24KB) replace f32 rows (50.7KB); MLP K-chunked.
//   LDS ~50.5KB -> 3 blocks/CU (was 2).
// - Weights pre-packed f32->bf16 B-fragments in d_ws (validated round 4).
// ============================================================================

#define NP 32
#define NE 128
#define NSEQ (64 * 256)
#define NMLP 512
#define NDEPTH 4
#define LST 132     // f32 LDS row stride (residual)
#define HBS 136     // bf16 LDS row stride (E=128 A-tiles)
#define H1C 264     // bf16 LDS row stride (MLP 256-col chunk)

// packed-weight element offsets inside ws (u16 units, after 64B header)
#define QKV_W_OFF 0
#define O_W_OFF   196608
#define M1_W_OFF  262144
#define M2_W_OFF  524288
#define D1_W_OFF  786432
#define W_TOTAL   851968
#define WS_NEED   (64 + (size_t)W_TOTAL * 2)

typedef unsigned short u16;
typedef unsigned int u32;
typedef __attribute__((ext_vector_type(8))) short bf16x8;
typedef __attribute__((ext_vector_type(4))) float f32x4;
#define MFMA16 __builtin_amdgcn_mfma_f32_16x16x32_bf16

__device__ __forceinline__ float b2f(u16 u) {
  union { u32 i; float f; } v; v.i = ((u32)u) << 16; return v.f;
}
__device__ __forceinline__ u16 f2b(float f) {  // RNE f32 -> bf16
  union { float f; u32 i; } v; v.f = f;
  u32 x = v.i;
  x += 0x7fffu + ((x >> 16) & 1u);
  return (u16)(x >> 16);
}
__device__ __forceinline__ u32 pk2(float lo, float hi) {
  return (u32)f2b(lo) | ((u32)f2b(hi) << 16);
}
__device__ __forceinline__ float gelu_f(float x) {
  return 0.5f * x * (1.0f + erff(x * 0.7071067811865475f));
}

struct Args {
  const float *pos, *ctr, *ang;
  const int *sel;
  const float *Wp, *bp, *Wpe1, *bpe1, *Wpe2, *bpe2, *ltype, *mtok;
  const float *Wqkv, *bqkv, *Wo, *bo, *ln1s, *ln1b, *Wm1, *bm1, *Wm2, *bm2;
  const float *ln2s, *ln2b, *lnfs, *lnfb, *Wd1, *bd1, *Wd2, *bd2;
  float* out;
  float* wsf;
  int* wsi;
};

// ---------------------------------------------------------------------------
// Weight pack: W[l][k][n] f32 -> bf16 fragments. dst element
// (((l*NT+nt)*KT+kt)*64 + lane)*8 + j = W[l][kt*32+(lane>>4)*8+j][nt*16+(lane&15)]
// ---------------------------------------------------------------------------
__global__ void pack_w(const float* __restrict__ src, u16* __restrict__ dst,
                       int K, int N, int L) {
  int id = blockIdx.x * 256 + threadIdx.x;
  int KT = K >> 5, NT = N >> 4;
  int total = L * NT * KT * 64;
  if (id >= total) return;
  int lane = id & 63;
  int rest = id >> 6;
  int kt = rest % KT;
  int rest2 = rest / KT;
  int nt = rest2 % NT;
  int l = rest2 / NT;
  const float* s = src + (size_t)l * K * N + (size_t)(kt * 32 + (lane >> 4) * 8) * N
                 + nt * 16 + (lane & 15);
  u16 tmp[8];
#pragma unroll
  for (int j = 0; j < 8; ++j) tmp[j] = f2b(s[(size_t)j * N]);
  ((uint4*)dst)[id] = *(const uint4*)tmp;
}

// ---------------------------------------------------------------------------
// GEMM: wave computes 32 x (NTW*16) slab, K=128 (KT=4), A bf16 in LDS (stride SA)
// ---------------------------------------------------------------------------
template <int NTW>
__device__ __forceinline__ void gemm_kt4(const u16* __restrict__ hA, int SA,
                                         const u16* __restrict__ B, int w,
                                         int lane, f32x4 (&acc)[NTW][2]) {
  int ar = lane & 15, ac = (lane >> 4) * 8;
  bf16x8 af[8];
#pragma unroll
  for (int kb = 0; kb < 4; ++kb) {
    af[kb]     = *(const bf16x8*)(hA + ar * SA + kb * 32 + ac);
    af[kb + 4] = *(const bf16x8*)(hA + (ar + 16) * SA + kb * 32 + ac);
  }
#pragma unroll
  for (int i = 0; i < NTW; ++i) {
    int nt = w + 4 * i;
    const u16* Bp = B + (size_t)nt * 2048 + lane * 8;
    f32x4 z = {0.f, 0.f, 0.f, 0.f};
    acc[i][0] = z; acc[i][1] = z;
#pragma unroll
    for (int kb = 0; kb < 4; ++kb) {
      bf16x8 b = *(const bf16x8*)(Bp + kb * 512);
      acc[i][0] = MFMA16(af[kb], b, acc[i][0], 0, 0, 0);
      acc[i][1] = MFMA16(af[kb + 4], b, acc[i][1], 0, 0, 0);
    }
  }
}

// K=256 chunk (kt 8), A stride H1C, 2 ntiles/wave, ACCUMULATES into acc.
__device__ __forceinline__ void gemm_kt8_acc(const u16* __restrict__ hA,
                                             const u16* __restrict__ B, int ktoff,
                                             int w, int lane, f32x4 (&acc)[2][2]) {
  int ar = lane & 15, ac = (lane >> 4) * 8;
#pragma unroll
  for (int ktl = 0; ktl < 8; ++ktl) {
    bf16x8 a0 = *(const bf16x8*)(hA + ar * H1C + ktl * 32 + ac);
    bf16x8 a1 = *(const bf16x8*)(hA + (ar + 16) * H1C + ktl * 32 + ac);
#pragma unroll
    for (int i = 0; i < 2; ++i) {
      int nt = w + 4 * i;
      bf16x8 b = *(const bf16x8*)(B + (size_t)nt * 8192 + (size_t)(ktoff + ktl) * 512 + lane * 8);
      acc[i][0] = MFMA16(a0, b, acc[i][0], 0, 0, 0);
      acc[i][1] = MFMA16(a1, b, acc[i][1], 0, 0, 0);
    }
  }
}

// LN(src f32 [32][LST]) * gam + bet -> dst bf16 [32][HBS]
__device__ __forceinline__ void layer_norm_bf(const float* __restrict__ src,
                                              u16* __restrict__ dst,
                                              const float* gam, const float* bet,
                                              int t, float* mrow, float* vrow) {
  int p = t >> 3, j0 = (t & 7) * 16;
  const float* row = src + p * LST + j0;
  float sum = 0.f, sq = 0.f;
#pragma unroll
  for (int k = 0; k < 16; ++k) { float v = row[k]; sum += v; sq += v * v; }
#pragma unroll
  for (int o = 1; o < 8; o <<= 1) { sum += __shfl_xor(sum, o); sq += __shfl_xor(sq, o); }
  if ((t & 7) == 0) {
    float m = sum * 0.0078125f;
    mrow[p] = m;
    vrow[p] = sq * 0.0078125f - m * m;
  }
  __syncthreads();
  float m = mrow[p], rs = rsqrtf(vrow[p] + 1e-5f);
  u32 wb[8];
#pragma unroll
  for (int k8 = 0; k8 < 4; ++k8) {
    float4 v = ((const float4*)row)[k8];
    float4 g = ((const float4*)(gam + j0))[k8];
    float4 b = ((const float4*)(bet + j0))[k8];
    wb[k8 * 2]     = pk2((v.x - m) * rs * g.x + b.x, (v.y - m) * rs * g.y + b.y);
    wb[k8 * 2 + 1] = pk2((v.z - m) * rs * g.z + b.z, (v.w - m) * rs * g.w + b.w);
  }
  uint4* dp = (uint4*)(dst + p * HBS + j0);
  dp[0] = make_uint4(wb[0], wb[1], wb[2], wb[3]);
  dp[1] = make_uint4(wb[4], wb[5], wb[6], wb[7]);
  __syncthreads();
}

__global__ __launch_bounds__(256, 3) void mrm_main_mfma(Args a, const u16* __restrict__ wsW) {
  __shared__ float xs[32 * LST];                 // residual f32, 16896 B
  __shared__ u16 hbf[32 * HBS];                  // bf16 A-tiles, 8704 B
  __shared__ __align__(16) u32 uni4[6144];       // 24576 B union
  __shared__ float mrow[32], vrow[32];
  __shared__ int selv[32];
  __shared__ float lacc;

  // union views
  u16* qbuf = (u16*)uni4;                        // [8 h][32 q][16 d]  (Q*0.25)
  u16* kbuf = qbuf + 4096;                       // [8 h][32 k][16 d]
  u16* vbuf = kbuf + 4096;                       // [8 h][16 d][32 k]  (transposed)
  u32* vbuf_w = (u32*)vbuf;
  u16* h1c  = (u16*)uni4;                        // [32][H1C] MLP chunk
  float* wd2s = (float*)uni4 + 4224;             // 1024 f32 @ byte 16896
  float* tvec = (float*)uni4;                    // prologue only
  float* pvec = (float*)uni4 + 128;

  const int s = blockIdx.x;
  const int t = threadIdx.x;
  const int w = t >> 6, lane = t & 63;
  const int cr = lane & 15, rq = (lane >> 4) * 4;
  const int rg = t >> 5, cg = t & 31, r0 = rg * 4, c0 = cg * 4;

  if (t == 0) lacc = 0.f;
  if (t < 32) selv[t] = a.sel[s * NP + t];

  const float cx = a.ctr[s * 2 + 0];
  const float cy = a.ctr[s * 2 + 1];
  const float an = a.ang[s];
  const float ca = cosf(an), sa = sinf(an);

  // ---- positional embedding (VALU, tiny) ----
  if (t < 128) {
    float accp = a.bpe1[t] + cx * a.Wpe1[t] + cy * a.Wpe1[128 + t]
               + ca * a.Wpe1[256 + t] + sa * a.Wpe1[384 + t];
    tvec[t] = gelu_f(accp);
  }
  __syncthreads();
  if (t < 128) {
    float accp = a.bpe2[t];
    for (int e = 0; e < 128; ++e) accp += tvec[e] * a.Wpe2[e * 128 + t];
    pvec[t] = accp;
  }
  __syncthreads();

  // ---- token build -> xs f32 ----
  {
    float4 w0v = *(const float4*)(a.Wp + c0);
    float4 w1v = *(const float4*)(a.Wp + NE + c0);
    float4 bpv = *(const float4*)(a.bp + c0);
    float4 ltv = *(const float4*)(a.ltype + c0);
    float4 mtv = *(const float4*)(a.mtok + c0);
    float a0 = bpv.x + pvec[c0 + 0] + ltv.x;
    float a1 = bpv.y + pvec[c0 + 1] + ltv.y;
    float a2 = bpv.z + pvec[c0 + 2] + ltv.z;
    float a3 = bpv.w + pvec[c0 + 3] + ltv.w;
#pragma unroll
    for (int rr = 0; rr < 4; ++rr) {
      int p = r0 + rr;
      float px = a.pos[(s * NP + p) * 2 + 0] - cx;
      float py = a.pos[(s * NP + p) * 2 + 1] - cy;
      bool mk = selv[p] != 0;
      float4 o;
      o.x = mk ? mtv.x : (px * w0v.x + py * w1v.x + a0);
      o.y = mk ? mtv.y : (px * w0v.y + py * w1v.y + a1);
      o.z = mk ? mtv.z : (px * w0v.z + py * w1v.z + a2);
      o.w = mk ? mtv.w : (px * w0v.w + py * w1v.w + a3);
      *(float4*)&xs[p * LST + c0] = o;
    }
  }
  __syncthreads();

  // ---- layers ----
  for (int li = 0; li < NDEPTH; ++li) {
    const u16* qkvW = wsW + QKV_W_OFF + li * 49152;
    const u16* oW   = wsW + O_W_OFF   + li * 16384;
    const u16* m1W  = wsW + M1_W_OFF  + li * 65536;
    const u16* m2W  = wsW + M2_W_OFF  + li * 65536;
    const float* bqkv_i = a.bqkv + li * 384;
    const float* bo_i   = a.bo + li * NE;
    const float* bm1_i  = a.bm1 + li * NMLP;
    const float* bm2_i  = a.bm2 + li * NE;

    layer_norm_bf(xs, hbf, a.ln1s + li * NE, a.ln1b + li * NE, t, mrow, vrow);

    // ---- QKV GEMM -> bf16 q/k/v tiles (Q pre-scaled by 0.25, V transposed) ----
    {
      f32x4 acc[6][2];
      gemm_kt4<6>(hbf, HBS, qkvW, w, lane, acc);
#pragma unroll
      for (int i = 0; i < 6; ++i) {
        int nt = w + 4 * i;                 // i<2: Q(nt 0-7); i<4: K(8-15); else V(16-23)
        int n = nt * 16 + cr;
        float bias = bqkv_i[n];
        float v0[4], v1[4];
#pragma unroll
        for (int j = 0; j < 4; ++j) { v0[j] = acc[i][0][j] + bias; v1[j] = acc[i][1][j] + bias; }
        if (i < 2) {                        // Q: qbuf[h][q][d] scaled
          u16* qb = qbuf + nt * 512 + cr;
#pragma unroll
          for (int j = 0; j < 4; ++j) {
            qb[(rq + j) * 16]      = f2b(v0[j] * 0.25f);
            qb[(rq + j + 16) * 16] = f2b(v1[j] * 0.25f);
          }
        } else if (i < 4) {                 // K: kbuf[h][k][d]
          u16* kb = kbuf + (nt - 8) * 512 + cr;
#pragma unroll
          for (int j = 0; j < 4; ++j) {
            kb[(rq + j) * 16]      = f2b(v0[j]);
            kb[(rq + j + 16) * 16] = f2b(v1[j]);
          }
        } else {                            // V transposed: vbuf[h][d][k], u32-packed
          u32* vb = vbuf_w + (nt - 16) * 256 + cr * 16 + (rq >> 1);
          vb[0] = pk2(v0[0], v0[1]);
          vb[1] = pk2(v0[2], v0[3]);
          vb[8] = pk2(v1[0], v1[1]);
          vb[9] = pk2(v1[2], v1[3]);
        }
      }
    }
    __syncthreads();

    // ---- attention (MFMA): wave w owns heads {2w, 2w+1} ----
    {
      const int l15 = lane & 15, gl = lane >> 4;
      const int bpa_base = (l15 + ((gl & 1) << 5)) << 2;   // src_lane*4 base
      const f32x4 z = {0.f, 0.f, 0.f, 0.f};
#pragma unroll
      for (int hi = 0; hi < 2; ++hi) {
        const int h = 2 * w + hi;
        const u16* qb = qbuf + h * 512;
        const u16* kb = kbuf + h * 512;
        bf16x8 vf = *(const bf16x8*)(vbuf + h * 512 + l15 * 32 + gl * 8);
        bf16x8 kf0 = {}, kf1 = {};
        if (gl < 2) {     // zero-padded K dimension: only d'=0..15 is real
          kf0 = *(const bf16x8*)(kb + l15 * 16 + gl * 8);
          kf1 = *(const bf16x8*)(kb + (16 + l15) * 16 + gl * 8);
        }
#pragma unroll
        for (int qt = 0; qt < 2; ++qt) {
          bf16x8 qf = {};
          if (gl < 2) qf = *(const bf16x8*)(qb + (qt * 16 + l15) * 16 + gl * 8);
          // S^T tiles: rows=keys, cols=queries (scale folded into Q)
          f32x4 s0 = MFMA16(kf0, qf, z, 0, 0, 0);    // keys 0-15
          f32x4 s1 = MFMA16(kf1, qf, z, 0, 0, 0);    // keys 16-31
          float mx = fmaxf(fmaxf(fmaxf(s0[0], s0[1]), fmaxf(s0[2], s0[3])),
                           fmaxf(fmaxf(s1[0], s1[1]), fmaxf(s1[2], s1[3])));
          mx = fmaxf(mx, __shfl_xor(mx, 16));
          mx = fmaxf(mx, __shfl_xor(mx, 32));
          float p0 = __expf(s0[0] - mx), p1 = __expf(s0[1] - mx);
          float p2 = __expf(s0[2] - mx), p3 = __expf(s0[3] - mx);
          float p4 = __expf(s1[0] - mx), p5 = __expf(s1[1] - mx);
          float p6 = __expf(s1[2] - mx), p7 = __expf(s1[3] - mx);
          float sum = ((p0 + p1) + (p2 + p3)) + ((p4 + p5) + (p6 + p7));
          sum += __shfl_xor(sum, 16);
          sum += __shfl_xor(sum, 32);
          float inv = 1.f / sum;
          u32 pw0 = pk2(p0 * inv, p1 * inv), pw1 = pk2(p2 * inv, p3 * inv);
          u32 pw2 = pk2(p4 * inv, p5 * inv), pw3 = pk2(p6 * inv, p7 * inv);
          // build PV A-frag: lane needs P[q=l15][k=8*gl+jj] via bpermute
          union { u32 uw[4]; bf16x8 v; } pa;
#pragma unroll
          for (int ww = 0; ww < 4; ++ww) {
            int addr = bpa_base + ((ww >> 1) << 6);
            u32 lo = __builtin_amdgcn_ds_bpermute(addr, (int)((ww & 1) ? pw1 : pw0));
            u32 hi2 = __builtin_amdgcn_ds_bpermute(addr, (int)((ww & 1) ? pw3 : pw2));
            pa.uw[ww] = (gl < 2) ? lo : hi2;
          }
          f32x4 o = MFMA16(pa.v, vf, z, 0, 0, 0);    // O[q 16][d 16], full K=32
#pragma unroll
          for (int j = 0; j < 4; ++j)
            hbf[(qt * 16 + gl * 4 + j) * HBS + h * 16 + l15] = f2b(o[j]);
        }
      }
    }
    __syncthreads();

    // ---- proj: attn_out(bf16) @ Wo -> xs += ----
    {
      f32x4 acc[2][2];
      gemm_kt4<2>(hbf, HBS, oW, w, lane, acc);
#pragma unroll
      for (int i = 0; i < 2; ++i) {
        int n = (w + 4 * i) * 16 + cr;
        float bias = bo_i[n];
#pragma unroll
        for (int j = 0; j < 4; ++j) {
          xs[(rq + j) * LST + n]      += acc[i][0][j] + bias;
          xs[(rq + j + 16) * LST + n] += acc[i][1][j] + bias;
        }
      }
    }
    __syncthreads();

    layer_norm_bf(xs, hbf, a.ln2s + li * NE, a.ln2b + li * NE, t, mrow, vrow);

    // ---- MLP, K-chunked (2 x 256 cols) to keep LDS small ----
    {
      f32x4 acc2[2][2];
      f32x4 z = {0.f, 0.f, 0.f, 0.f};
      acc2[0][0] = z; acc2[0][1] = z; acc2[1][0] = z; acc2[1][1] = z;
#pragma unroll
      for (int ch = 0; ch < 2; ++ch) {
        {
          f32x4 acc[4][2];
          gemm_kt4<4>(hbf, HBS, m1W + ch * 32768, w, lane, acc);
#pragma unroll
          for (int i = 0; i < 4; ++i) {
            int nl = (w + 4 * i) * 16 + cr;
            float bias = bm1_i[ch * 256 + nl];
#pragma unroll
            for (int j = 0; j < 4; ++j) {
              h1c[(rq + j) * H1C + nl]      = f2b(gelu_f(acc[i][0][j] + bias));
              h1c[(rq + j + 16) * H1C + nl] = f2b(gelu_f(acc[i][1][j] + bias));
            }
          }
        }
        __syncthreads();
        gemm_kt8_acc(h1c, m2W, ch * 8, w, lane, acc2);
        __syncthreads();
      }
      {
        f32x4* a2 = &acc2[0][0];
#pragma unroll
        for (int i = 0; i < 2; ++i) {
          int n = (w + 4 * i) * 16 + cr;
          float bias = bm2_i[n];
#pragma unroll
          for (int j = 0; j < 4; ++j) {
            xs[(rq + j) * LST + n]      += acc2[i][0][j] + bias;
            xs[(rq + j + 16) * LST + n] += acc2[i][1][j] + bias;
          }
        }
        (void)a2;
      }
    }
    __syncthreads();
  }

  // ---- final LN -> hbf ----
  layer_norm_bf(xs, hbf, a.lnfs, a.lnfb, t, mrow, vrow);

  // preload Wd2 f32 (region disjoint from h1c; ordered by the d1 barrier)
  for (int i = t; i < 1024; i += 256) wd2s[i] = a.Wd2[i];

  // ---- decoder, K-chunked ----
  float yacc = 0.f;
  const int pdec = t >> 3, dd2 = (t >> 2) & 1, q4 = t & 3;
#pragma unroll
  for (int ch = 0; ch < 2; ++ch) {
    {
      f32x4 acc[4][2];
      gemm_kt4<4>(hbf, HBS, wsW + D1_W_OFF + ch * 32768, w, lane, acc);
#pragma unroll
      for (int i = 0; i < 4; ++i) {
        int nl = (w + 4 * i) * 16 + cr;
        float bias = a.bd1[ch * 256 + nl];
#pragma unroll
        for (int j = 0; j < 4; ++j) {
          h1c[(rq + j) * H1C + nl]      = f2b(fmaxf(acc[i][0][j] + bias, 0.f));
          h1c[(rq + j + 16) * H1C + nl] = f2b(fmaxf(acc[i][1][j] + bias, 0.f));
        }
      }
    }
    __syncthreads();
    {
      const u16* hrow = h1c + pdec * H1C + q4 * 64;
      const float* wp = wd2s + (ch * 256 + q4 * 64) * 2 + dd2;
#pragma unroll
      for (int k8 = 0; k8 < 8; ++k8) {
        bf16x8 hv = *(const bf16x8*)(hrow + k8 * 8);
#pragma unroll
        for (int jj = 0; jj < 8; ++jj)
          yacc += b2f((u16)hv[jj]) * wp[(k8 * 8 + jj) * 2];
      }
    }
    __syncthreads();
  }

  // ---- y write + loss partial ----
  {
    yacc += __shfl_xor(yacc, 1);
    yacc += __shfl_xor(yacc, 2);
    if (q4 == 0) {
      float y = yacc + a.bd2[dd2];
      a.out[1 + (s * NP + pdec) * 2 + dd2] = y;
      float lnm = a.pos[(s * NP + pdec) * 2 + dd2] - (dd2 ? cy : cx);
      float d = y - lnm;
      if (selv[pdec] != 0) atomicAdd(&lacc, d * d);
    }
  }
  __syncthreads();
  if (t == 0) {
    atomicAdd(a.wsf, lacc);
    int cnt = 0;
#pragma unroll
    for (int p = 0; p < NP; ++p) cnt += (selv[p] != 0) ? 1 : 0;
    atomicAdd(a.wsi, cnt);
  }
}

// ============================================================================
// Round-3 VALU fallback (used only if ws_size < WS_NEED)
// ============================================================================
__device__ __forceinline__ void mm128(const float* __restrict__ src,
                                      const float* __restrict__ W, int ldw,
                                      int r0, int cabs, float acc[4][4]) {
#pragma unroll 4
  for (int k = 0; k < NE; ++k) {
    float4 wv = *(const float4*)(W + k * ldw + cabs);
#pragma unroll
    for (int rr = 0; rr < 4; ++rr) {
      float sv = src[(r0 + rr) * LST + k];
      acc[rr][0] += sv * wv.x; acc[rr][1] += sv * wv.y;
      acc[rr][2] += sv * wv.z; acc[rr][3] += sv * wv.w;
    }
  }
}

__device__ __forceinline__ void layer_norm(const float* __restrict__ src,
                                           float* __restrict__ dst,
                                           const float* gam, const float* bet,
                                           int t, float* mrow, float* vrow) {
  {
    int p = t >> 3, j = t & 7;
    const float* row = src + p * LST + j * 16;
    float sum = 0.f, sq = 0.f;
#pragma unroll
    for (int k2 = 0; k2 < 16; ++k2) { float v = row[k2]; sum += v; sq += v * v; }
#pragma unroll
    for (int o = 1; o < 8; o <<= 1) { sum += __shfl_xor(sum, o); sq += __shfl_xor(sq, o); }
    if (j == 0) {
      float m = sum * 0.0078125f;
      mrow[p] = m;
      vrow[p] = sq * 0.0078125f - m * m;
    }
  }
  __syncthreads();
  {
    int rg = t >> 5, cg = t & 31, r0 = rg * 4, c0 = cg * 4;
    float4 gv = *(const float4*)(gam + c0);
    float4 bv = *(const float4*)(bet + c0);
#pragma unroll
    for (int rr = 0; rr < 4; ++rr) {
      int r = r0 + rr;
      float m = mrow[r], rs = rsqrtf(vrow[r] + 1e-5f);
      float4 v = *(const float4*)&src[r * LST + c0];
      float4 o;
      o.x = (v.x - m) * rs * gv.x + bv.x;
      o.y = (v.y - m) * rs * gv.y + bv.y;
      o.z = (v.z - m) * rs * gv.z + bv.z;
      o.w = (v.w - m) * rs * gv.w + bv.w;
      *(float4*)&dst[r * LST + c0] = o;
    }
  }
  __syncthreads();
}

__global__ __launch_bounds__(256, 2) void mrm_main_valu(Args a) {
  __shared__ float xs[32 * LST];
  __shared__ float hs[32 * LST];
  __shared__ float ts[32 * LST];
  __shared__ float qs[32 * 17];
  __shared__ float ks2[32 * 17];
  __shared__ float vs[32 * 17];
  __shared__ float ss[32 * 33];
  __shared__ float tvec[128];
  __shared__ float pvec[128];
  __shared__ float mrow[32], vrow[32], srow[32];
  __shared__ int selv[32];

  const int s = blockIdx.x;
  const int t = threadIdx.x;
  const int rg = t >> 5, cg = t & 31, r0 = rg * 4, c0 = cg * 4;

  if (t < 32) selv[t] = a.sel[s * NP + t];

  const float cx = a.ctr[s * 2 + 0];
  const float cy = a.ctr[s * 2 + 1];
  const float an = a.ang[s];
  const float ca = cosf(an), sa = sinf(an);

  if (t < 128) {
    float accp = a.bpe1[t] + cx * a.Wpe1[t] + cy * a.Wpe1[128 + t]
               + ca * a.Wpe1[256 + t] + sa * a.Wpe1[384 + t];
    tvec[t] = gelu_f(accp);
  }
  __syncthreads();
  if (t < 128) {
    float accp = a.bpe2[t];
    for (int e = 0; e < 128; ++e) accp += tvec[e] * a.Wpe2[e * 128 + t];
    pvec[t] = accp;
  }
  __syncthreads();

  {
    float4 w0v = *(const float4*)(a.Wp + c0);
    float4 w1v = *(const float4*)(a.Wp + NE + c0);
    float4 bpv = *(const float4*)(a.bp + c0);
    float4 ltv = *(const float4*)(a.ltype + c0);
    float4 mtv = *(const float4*)(a.mtok + c0);
    float a0 = bpv.x + pvec[c0 + 0] + ltv.x;
    float a1 = bpv.y + pvec[c0 + 1] + ltv.y;
    float a2 = bpv.z + pvec[c0 + 2] + ltv.z;
    float a3 = bpv.w + pvec[c0 + 3] + ltv.w;
#pragma unroll
    for (int rr = 0; rr < 4; ++rr) {
      int p = r0 + rr;
      float px = a.pos[(s * NP + p) * 2 + 0] - cx;
      float py = a.pos[(s * NP + p) * 2 + 1] - cy;
      bool mk = selv[p] != 0;
      float4 o;
      o.x = mk ? mtv.x : (px * w0v.x + py * w1v.x + a0);
      o.y = mk ? mtv.y : (px * w0v.y + py * w1v.y + a1);
      o.z = mk ? mtv.z : (px * w0v.z + py * w1v.z + a2);
      o.w = mk ? mtv.w : (px * w0v.w + py * w1v.w + a3);
      *(float4*)&xs[p * LST + c0] = o;
    }
  }
  __syncthreads();

  const int dd = t & 15, ph = t >> 4;

  for (int li = 0; li < NDEPTH; ++li) {
    const float* Wqkv_i = a.Wqkv + li * NE * 3 * NE;
    const float* bqkv_i = a.bqkv + li * 3 * NE;
    const float* Wo_i   = a.Wo   + li * NE * NE;
    const float* bo_i   = a.bo   + li * NE;
    const float* Wm1_i  = a.Wm1  + li * NE * NMLP;
    const float* bm1_i  = a.bm1  + li * NMLP;
    const float* Wm2_i  = a.Wm2  + li * NMLP * NE;
    const float* bm2_i  = a.bm2  + li * NE;

    layer_norm(xs, hs, a.ln1s + li * NE, a.ln1b + li * NE, t, mrow, vrow);

    for (int hh = 0; hh < 8; ++hh) {
      float aq0 = 0, aq1 = 0, ak0 = 0, ak1 = 0, av0 = 0, av1 = 0;
      const float* wcol = Wqkv_i + hh * 16 + dd;
#pragma unroll 4
      for (int k2 = 0; k2 < NE; ++k2) {
        const float* wr = wcol + k2 * (3 * NE);
        float wq = wr[0], wk = wr[NE], wv = wr[2 * NE];
        float h0 = hs[ph * LST + k2], h1 = hs[(ph + 16) * LST + k2];
        aq0 += h0 * wq; aq1 += h1 * wq;
        ak0 += h0 * wk; ak1 += h1 * wk;
        av0 += h0 * wv; av1 += h1 * wv;
      }
      {
        float bq = bqkv_i[hh * 16 + dd];
        float bk = bqkv_i[NE + hh * 16 + dd];
        float bv = bqkv_i[2 * NE + hh * 16 + dd];
        qs[ph * 17 + dd] = aq0 + bq;  qs[(ph + 16) * 17 + dd] = aq1 + bq;
        ks2[ph * 17 + dd] = ak0 + bk; ks2[(ph + 16) * 17 + dd] = ak1 + bk;
        vs[ph * 17 + dd] = av0 + bv;  vs[(ph + 16) * 17 + dd] = av1 + bv;
      }
      __syncthreads();
      {
        int pk = t & 31, pb = t >> 5;
#pragma unroll
        for (int ii = 0; ii < 4; ++ii) {
          int p = pb + 8 * ii;
          float acc = 0.f;
#pragma unroll
          for (int d2 = 0; d2 < 16; ++d2) acc += qs[p * 17 + d2] * ks2[pk * 17 + d2];
          ss[p * 33 + pk] = 0.25f * acc;
        }
      }
      __syncthreads();
      {
        int p = t >> 3, j = t & 7;
        float v0 = ss[p * 33 + j * 4 + 0], v1 = ss[p * 33 + j * 4 + 1];
        float v2 = ss[p * 33 + j * 4 + 2], v3 = ss[p * 33 + j * 4 + 3];
        float mx = fmaxf(fmaxf(v0, v1), fmaxf(v2, v3));
#pragma unroll
        for (int o = 1; o < 8; o <<= 1) mx = fmaxf(mx, __shfl_xor(mx, o));
        v0 = expf(v0 - mx); v1 = expf(v1 - mx); v2 = expf(v2 - mx); v3 = expf(v3 - mx);
        float sm = v0 + v1 + v2 + v3;
#pragma unroll
        for (int o = 1; o < 8; o <<= 1) sm += __shfl_xor(sm, o);
        ss[p * 33 + j * 4 + 0] = v0; ss[p * 33 + j * 4 + 1] = v1;
        ss[p * 33 + j * 4 + 2] = v2; ss[p * 33 + j * 4 + 3] = v3;
        if (j == 0) srow[p] = sm;
      }
      __syncthreads();
      {
        float o0 = 0.f, o1 = 0.f;
#pragma unroll
        for (int pk = 0; pk < 32; ++pk) {
          float vv = vs[pk * 17 + dd];
          o0 += ss[ph * 33 + pk] * vv;
          o1 += ss[(ph + 16) * 33 + pk] * vv;
        }
        ts[ph * LST + hh * 16 + dd] = o0 / srow[ph];
        ts[(ph + 16) * LST + hh * 16 + dd] = o1 / srow[ph + 16];
      }
      __syncthreads();
    }

    {
      float acc[4][4] = {};
      mm128(ts, Wo_i, NE, r0, c0, acc);
      float4 bv = *(const float4*)(bo_i + c0);
#pragma unroll
      for (int rr = 0; rr < 4; ++rr) {
        float4 v = *(float4*)&xs[(r0 + rr) * LST + c0];
        v.x += acc[rr][0] + bv.x; v.y += acc[rr][1] + bv.y;
        v.z += acc[rr][2] + bv.z; v.w += acc[rr][3] + bv.w;
        *(float4*)&xs[(r0 + rr) * LST + c0] = v;
      }
    }
    __syncthreads();

    layer_norm(xs, hs, a.ln2s + li * NE, a.ln2b + li * NE, t, mrow, vrow);

    {
      float acc2[4][4] = {};
      for (int ch = 0; ch < 4; ++ch) {
        float acc[4][4] = {};
        mm128(hs, Wm1_i, NMLP, r0, ch * 128 + c0, acc);
        float4 bv = *(const float4*)(bm1_i + ch * 128 + c0);
#pragma unroll
        for (int rr = 0; rr < 4; ++rr) {
          float4 o;
          o.x = gelu_f(acc[rr][0] + bv.x); o.y = gelu_f(acc[rr][1] + bv.y);
          o.z = gelu_f(acc[rr][2] + bv.z); o.w = gelu_f(acc[rr][3] + bv.w);
          *(float4*)&ts[(r0 + rr) * LST + c0] = o;
        }
        __syncthreads();
        mm128(ts, Wm2_i + ch * 128 * NE, NE, r0, c0, acc2);
        __syncthreads();
      }
      float4 bv = *(const float4*)(bm2_i + c0);
#pragma unroll
      for (int rr = 0; rr < 4; ++rr) {
        float4 v = *(float4*)&xs[(r0 + rr) * LST + c0];
        v.x += acc2[rr][0] + bv.x; v.y += acc2[rr][1] + bv.y;
        v.z += acc2[rr][2] + bv.z; v.w += acc2[rr][3] + bv.w;
        *(float4*)&xs[(r0 + rr) * LST + c0] = v;
      }
    }
    __syncthreads();
  }

  layer_norm(xs, hs, a.lnfs, a.lnfb, t, mrow, vrow);

  float yacc = 0.f;
  const int pdec = t >> 1, ddec = t & 1;
  for (int ch = 0; ch < 4; ++ch) {
    {
      float acc[4][4] = {};
      mm128(hs, a.Wd1, NMLP, r0, ch * 128 + c0, acc);
      float4 bv = *(const float4*)(a.bd1 + ch * 128 + c0);
#pragma unroll
      for (int rr = 0; rr < 4; ++rr) {
        float4 o;
        o.x = fmaxf(acc[rr][0] + bv.x, 0.f); o.y = fmaxf(acc[rr][1] + bv.y, 0.f);
        o.z = fmaxf(acc[rr][2] + bv.z, 0.f); o.w = fmaxf(acc[rr][3] + bv.w, 0.f);
        *(float4*)&ts[(r0 + rr) * LST + c0] = o;
      }
    }
    __syncthreads();
    if (t < 64) {
#pragma unroll 4
      for (int k2 = 0; k2 < 128; ++k2)
        yacc += ts[pdec * LST + k2] * a.Wd2[(ch * 128 + k2) * 2 + ddec];
    }
    __syncthreads();
  }

  if (t < 64) {
    float y = yacc + a.bd2[ddec];
    a.out[1 + (s * NP + pdec) * 2 + ddec] = y;
    float lnm = a.pos[(s * NP + pdec) * 2 + ddec] - (ddec ? cy : cx);
    float d = y - lnm;
    float part = (selv[pdec] != 0) ? d * d : 0.f;
#pragma unroll
    for (int o = 1; o < 64; o <<= 1) part += __shfl_xor(part, o);
    if (t == 0) {
      atomicAdd(a.wsf, part);
      int cnt = 0;
      for (int p = 0; p < NP; ++p) cnt += (selv[p] != 0) ? 1 : 0;
      atomicAdd(a.wsi, cnt);
    }
  }
}

__global__ void mrm_fin(const float* ws, float* out) {
  float num = ws[0];
  int cnt = ((const int*)ws)[1];
  float den = fmaxf((float)cnt * 2.0f, 1.0f);
  out[0] = num / den;
}

extern "C" void kernel_launch(void* const* d_in, const int* in_sizes, int n_in,
                              void* d_out, int out_size, void* d_ws, size_t ws_size,
                              hipStream_t stream) {
  (void)in_sizes; (void)n_in; (void)out_size;
  Args a;
  a.pos   = (const float*)d_in[0];
  a.ctr   = (const float*)d_in[1];
  a.ang   = (const float*)d_in[2];
  a.sel   = (const int*)d_in[4];
  a.Wp    = (const float*)d_in[5];
  a.bp    = (const float*)d_in[6];
  a.Wpe1  = (const float*)d_in[7];
  a.bpe1  = (const float*)d_in[8];
  a.Wpe2  = (const float*)d_in[9];
  a.bpe2  = (const float*)d_in[10];
  a.ltype = (const float*)d_in[11];
  a.mtok  = (const float*)d_in[12];
  a.Wqkv  = (const float*)d_in[13];
  a.bqkv  = (const float*)d_in[14];
  a.Wo    = (const float*)d_in[15];
  a.bo    = (const float*)d_in[16];
  a.ln1s  = (const float*)d_in[17];
  a.ln1b  = (const float*)d_in[18];
  a.Wm1   = (const float*)d_in[19];
  a.bm1   = (const float*)d_in[20];
  a.Wm2   = (const float*)d_in[21];
  a.bm2   = (const float*)d_in[22];
  a.ln2s  = (const float*)d_in[23];
  a.ln2b  = (const float*)d_in[24];
  a.lnfs  = (const float*)d_in[25];
  a.lnfb  = (const float*)d_in[26];
  a.Wd1   = (const float*)d_in[27];
  a.bd1   = (const float*)d_in[28];
  a.Wd2   = (const float*)d_in[29];
  a.bd2   = (const float*)d_in[30];
  a.out   = (float*)d_out;
  a.wsf   = (float*)d_ws;
  a.wsi   = ((int*)d_ws) + 1;

  hipMemsetAsync(d_ws, 0, 8, stream);
  if (ws_size >= WS_NEED) {
    u16* wsW = (u16*)((char*)d_ws + 64);
    pack_w<<<dim3(96),  dim3(256), 0, stream>>>(a.Wqkv, wsW + QKV_W_OFF, 128, 384, 4);
    pack_w<<<dim3(32),  dim3(256), 0, stream>>>(a.Wo,   wsW + O_W_OFF,   128, 128, 4);
    pack_w<<<dim3(128), dim3(256), 0, stream>>>(a.Wm1,  wsW + M1_W_OFF,  128, 512, 4);
    pack_w<<<dim3(128), dim3(256), 0, stream>>>(a.Wm2,  wsW + M2_W_OFF,  512, 128, 4);
    pack_w<<<dim3(32),  dim3(256), 0, stream>>>(a.Wd1,  wsW + D1_W_OFF,  128, 512, 1);
    mrm_main_mfma<<<dim3(NSEQ), dim3(256), 0, stream>>>(a, wsW);
  } else {
    mrm_main_valu<<<dim3(NSEQ), dim3(256), 0, stream>>>(a);
  }
  mrm_fin<<<dim3(1), dim3(1), 0, stream>>>((const float*)d_ws, (float*)d_out);
}

// Round 7
// 2376.554 us; speedup vs baseline: 7.8881x; 1.0407x over previous
//
#include <hip/hip_runtime.h>

// ============================================================================
// ModelMRM fused forward, round 7: round-6 structure with the bf16 conversion
// reverted to the PROVEN manual RNE bit-twiddle (inline-asm v_cvt_pk_bf16_f32
// was the round-6 regression: absmax 0.0215 -> 0.375).
// Kept from round 6: gelu via A&S 7.1.26 erf poly (~17 ops vs libm erff),
// biases folded into MFMA C-init (all-zero biases: exact), Q-scale folded
// into packed weights (pow2: exact), V^T LDS stride 40 (conflict pad).
// ============================================================================

#define NP 32
#define NE 128
#define NSEQ (64 * 256)
#define NMLP 512
#define NDEPTH 4
#define LST 132     // f32 LDS row stride (residual)
#define HBS 136     // bf16 LDS row stride (E=128 A-tiles)
#define H1C 264     // bf16 LDS row stride (MLP 256-col chunk)
#define VST 40      // bf16 V^T d-row stride (conflict pad, 80B: 16B-aligned reads)

// packed-weight element offsets inside ws (u16 units, after 64B header)
#define QKV_W_OFF 0
#define O_W_OFF   196608
#define M1_W_OFF  262144
#define M2_W_OFF  524288
#define D1_W_OFF  786432
#define W_TOTAL   851968
#define WS_NEED   (64 + (size_t)W_TOTAL * 2)

typedef unsigned short u16;
typedef unsigned int u32;
typedef __attribute__((ext_vector_type(8))) short bf16x8;
typedef __attribute__((ext_vector_type(4))) float f32x4;
#define MFMA16 __builtin_amdgcn_mfma_f32_16x16x32_bf16

__device__ __forceinline__ float b2f(u16 u) {
  union { u32 i; float f; } v; v.i = ((u32)u) << 16; return v.f;
}
__device__ __forceinline__ u16 f2b(float f) {  // RNE f32 -> bf16 (proven r3-r5)
  union { float f; u32 i; } v; v.f = f;
  u32 x = v.i;
  x += 0x7fffu + ((x >> 16) & 1u);
  return (u16)(x >> 16);
}
__device__ __forceinline__ u32 pk2(float lo, float hi) {
  return (u32)f2b(lo) | ((u32)f2b(hi) << 16);
}

// exact-enough gelu via A&S 7.1.26 erf (|eps| <= 1.5e-7), ~17 VALU ops
__device__ __forceinline__ float gelu_f(float x) {
  float z = fabsf(x) * 0.7071067811865476f;
  float t = __builtin_amdgcn_rcpf(fmaf(z, 0.3275911f, 1.0f));
  float poly = t * fmaf(t, fmaf(t, fmaf(t, fmaf(t, 1.061405429f, -1.453152027f),
                        1.421413741f), -0.284496736f), 0.254829592f);
  float e = __expf(-z * z);
  float erf_abs = fmaf(-poly, e, 1.0f);
  float erf = copysignf(erf_abs, x);
  return 0.5f * x * (1.0f + erf);
}

struct Args {
  const float *pos, *ctr, *ang;
  const int *sel;
  const float *Wp, *bp, *Wpe1, *bpe1, *Wpe2, *bpe2, *ltype, *mtok;
  const float *Wqkv, *bqkv, *Wo, *bo, *ln1s, *ln1b, *Wm1, *bm1, *Wm2, *bm2;
  const float *ln2s, *ln2b, *lnfs, *lnfb, *Wd1, *bd1, *Wd2, *bd2;
  float* out;
  float* wsf;
  int* wsi;
};

// ---------------------------------------------------------------------------
// Weight pack: W[l][k][n] f32 -> bf16 fragments. dst element
// (((l*NT+nt)*KT+kt)*64 + lane)*8 + j = W[l][kt*32+(lane>>4)*8+j][nt*16+(lane&15)]
// Columns < scaleN get multiplied by scale (folds the 0.25 Q-scale).
// ---------------------------------------------------------------------------
__global__ void pack_w(const float* __restrict__ src, u16* __restrict__ dst,
                       int K, int N, int L, int scaleN, float scale) {
  int id = blockIdx.x * 256 + threadIdx.x;
  int KT = K >> 5, NT = N >> 4;
  int total = L * NT * KT * 64;
  if (id >= total) return;
  int lane = id & 63;
  int rest = id >> 6;
  int kt = rest % KT;
  int rest2 = rest / KT;
  int nt = rest2 % NT;
  int l = rest2 / NT;
  int col = nt * 16 + (lane & 15);
  float sc = (col < scaleN) ? scale : 1.0f;
  const float* s = src + (size_t)l * K * N + (size_t)(kt * 32 + (lane >> 4) * 8) * N + col;
  u16 tmp[8];
#pragma unroll
  for (int j = 0; j < 8; ++j) tmp[j] = f2b(s[(size_t)j * N] * sc);
  ((uint4*)dst)[id] = *(const uint4*)tmp;
}

// ---------------------------------------------------------------------------
// GEMM: wave computes 32 x (NTW*16) slab, K=128 (KT=4), A bf16 in LDS (stride
// SA). Bias (indexed by output col) folded into the accumulator init.
// ---------------------------------------------------------------------------
template <int NTW>
__device__ __forceinline__ void gemm_kt4_b(const u16* __restrict__ hA, int SA,
                                           const u16* __restrict__ B, int w,
                                           int lane, const float* __restrict__ bias,
                                           f32x4 (&acc)[NTW][2]) {
  int ar = lane & 15, ac = (lane >> 4) * 8;
  bf16x8 af[8];
#pragma unroll
  for (int kb = 0; kb < 4; ++kb) {
    af[kb]     = *(const bf16x8*)(hA + ar * SA + kb * 32 + ac);
    af[kb + 4] = *(const bf16x8*)(hA + (ar + 16) * SA + kb * 32 + ac);
  }
#pragma unroll
  for (int i = 0; i < NTW; ++i) {
    int nt = w + 4 * i;
    const u16* Bp = B + (size_t)nt * 2048 + lane * 8;
    float bb = bias[nt * 16 + ar];
    f32x4 bi = {bb, bb, bb, bb};
    acc[i][0] = bi; acc[i][1] = bi;
#pragma unroll
    for (int kb = 0; kb < 4; ++kb) {
      bf16x8 b = *(const bf16x8*)(Bp + kb * 512);
      acc[i][0] = MFMA16(af[kb], b, acc[i][0], 0, 0, 0);
      acc[i][1] = MFMA16(af[kb + 4], b, acc[i][1], 0, 0, 0);
    }
  }
}

// K=256 chunk (kt 8), A stride H1C, 2 ntiles/wave, ACCUMULATES into acc.
__device__ __forceinline__ void gemm_kt8_acc(const u16* __restrict__ hA,
                                             const u16* __restrict__ B, int ktoff,
                                             int w, int lane, f32x4 (&acc)[2][2]) {
  int ar = lane & 15, ac = (lane >> 4) * 8;
#pragma unroll
  for (int ktl = 0; ktl < 8; ++ktl) {
    bf16x8 a0 = *(const bf16x8*)(hA + ar * H1C + ktl * 32 + ac);
    bf16x8 a1 = *(const bf16x8*)(hA + (ar + 16) * H1C + ktl * 32 + ac);
#pragma unroll
    for (int i = 0; i < 2; ++i) {
      int nt = w + 4 * i;
      bf16x8 b = *(const bf16x8*)(B + (size_t)nt * 8192 + (size_t)(ktoff + ktl) * 512 + lane * 8);
      acc[i][0] = MFMA16(a0, b, acc[i][0], 0, 0, 0);
      acc[i][1] = MFMA16(a1, b, acc[i][1], 0, 0, 0);
    }
  }
}

// LN(src f32 [32][LST]) * gam + bet -> dst bf16 [32][HBS]
__device__ __forceinline__ void layer_norm_bf(const float* __restrict__ src,
                                              u16* __restrict__ dst,
                                              const float* gam, const float* bet,
                                              int t, float* mrow, float* vrow) {
  int p = t >> 3, j0 = (t & 7) * 16;
  const float* row = src + p * LST + j0;
  float sum = 0.f, sq = 0.f;
#pragma unroll
  for (int k = 0; k < 16; ++k) { float v = row[k]; sum += v; sq += v * v; }
#pragma unroll
  for (int o = 1; o < 8; o <<= 1) { sum += __shfl_xor(sum, o); sq += __shfl_xor(sq, o); }
  if ((t & 7) == 0) {
    float m = sum * 0.0078125f;
    mrow[p] = m;
    vrow[p] = sq * 0.0078125f - m * m;
  }
  __syncthreads();
  float m = mrow[p], rs = rsqrtf(vrow[p] + 1e-5f);
  u32 wb[8];
#pragma unroll
  for (int k8 = 0; k8 < 4; ++k8) {
    float4 v = ((const float4*)row)[k8];
    float4 g = ((const float4*)(gam + j0))[k8];
    float4 b = ((const float4*)(bet + j0))[k8];
    wb[k8 * 2]     = pk2(fmaf((v.x - m) * rs, g.x, b.x), fmaf((v.y - m) * rs, g.y, b.y));
    wb[k8 * 2 + 1] = pk2(fmaf((v.z - m) * rs, g.z, b.z), fmaf((v.w - m) * rs, g.w, b.w));
  }
  uint4* dp = (uint4*)(dst + p * HBS + j0);
  dp[0] = make_uint4(wb[0], wb[1], wb[2], wb[3]);
  dp[1] = make_uint4(wb[4], wb[5], wb[6], wb[7]);
  __syncthreads();
}

__global__ __launch_bounds__(256, 3) void mrm_main_mfma(Args a, const u16* __restrict__ wsW) {
  __shared__ float xs[32 * LST];                 // residual f32, 16896 B
  __shared__ u16 hbf[32 * HBS];                  // bf16 A-tiles, 8704 B
  __shared__ __align__(16) u32 uni4[6656];       // 26624 B union
  __shared__ float mrow[32], vrow[32];
  __shared__ int selv[32];
  __shared__ float lacc;

  // union views
  u16* qbuf = (u16*)uni4;                        // [8 h][32 q][16 d]  (scale in W)
  u16* kbuf = qbuf + 4096;                       // [8 h][32 k][16 d]
  u16* vbuf = kbuf + 4096;                       // [8 h][16 d][VST]   (transposed, padded)
  u32* vbuf_w = (u32*)vbuf;
  u16* h1c  = (u16*)uni4;                        // [32][H1C] MLP chunk
  float* wd2s = (float*)uni4 + 4224;             // 1024 f32 @ byte 16896
  float* tvec = (float*)uni4;                    // prologue only
  float* pvec = (float*)uni4 + 128;

  const int s = blockIdx.x;
  const int t = threadIdx.x;
  const int w = t >> 6, lane = t & 63;
  const int cr = lane & 15, rq = (lane >> 4) * 4;
  const int rg = t >> 5, cg = t & 31, r0 = rg * 4, c0 = cg * 4;

  if (t == 0) lacc = 0.f;
  if (t < 32) selv[t] = a.sel[s * NP + t];

  const float cx = a.ctr[s * 2 + 0];
  const float cy = a.ctr[s * 2 + 1];
  const float an = a.ang[s];
  const float ca = cosf(an), sa = sinf(an);

  // ---- positional embedding (VALU, tiny) ----
  if (t < 128) {
    float accp = a.bpe1[t] + cx * a.Wpe1[t] + cy * a.Wpe1[128 + t]
               + ca * a.Wpe1[256 + t] + sa * a.Wpe1[384 + t];
    tvec[t] = gelu_f(accp);
  }
  __syncthreads();
  if (t < 128) {
    float accp = a.bpe2[t];
    for (int e = 0; e < 128; ++e) accp += tvec[e] * a.Wpe2[e * 128 + t];
    pvec[t] = accp;
  }
  __syncthreads();

  // ---- token build -> xs f32 ----
  {
    float4 w0v = *(const float4*)(a.Wp + c0);
    float4 w1v = *(const float4*)(a.Wp + NE + c0);
    float4 bpv = *(const float4*)(a.bp + c0);
    float4 ltv = *(const float4*)(a.ltype + c0);
    float4 mtv = *(const float4*)(a.mtok + c0);
    float a0 = bpv.x + pvec[c0 + 0] + ltv.x;
    float a1 = bpv.y + pvec[c0 + 1] + ltv.y;
    float a2 = bpv.z + pvec[c0 + 2] + ltv.z;
    float a3 = bpv.w + pvec[c0 + 3] + ltv.w;
#pragma unroll
    for (int rr = 0; rr < 4; ++rr) {
      int p = r0 + rr;
      float px = a.pos[(s * NP + p) * 2 + 0] - cx;
      float py = a.pos[(s * NP + p) * 2 + 1] - cy;
      bool mk = selv[p] != 0;
      float4 o;
      o.x = mk ? mtv.x : (px * w0v.x + py * w1v.x + a0);
      o.y = mk ? mtv.y : (px * w0v.y + py * w1v.y + a1);
      o.z = mk ? mtv.z : (px * w0v.z + py * w1v.z + a2);
      o.w = mk ? mtv.w : (px * w0v.w + py * w1v.w + a3);
      *(float4*)&xs[p * LST + c0] = o;
    }
  }
  __syncthreads();

  // ---- layers ----
  for (int li = 0; li < NDEPTH; ++li) {
    const u16* qkvW = wsW + QKV_W_OFF + li * 49152;
    const u16* oW   = wsW + O_W_OFF   + li * 16384;
    const u16* m1W  = wsW + M1_W_OFF  + li * 65536;
    const u16* m2W  = wsW + M2_W_OFF  + li * 65536;
    const float* bqkv_i = a.bqkv + li * 384;
    const float* bo_i   = a.bo + li * NE;
    const float* bm1_i  = a.bm1 + li * NMLP;
    const float* bm2_i  = a.bm2 + li * NE;

    layer_norm_bf(xs, hbf, a.ln1s + li * NE, a.ln1b + li * NE, t, mrow, vrow);

    // ---- QKV GEMM -> bf16 q/k/v tiles (Q*0.25 folded into W; V transposed) ----
    {
      f32x4 acc[6][2];
      {
        int ar = lane & 15, ac = (lane >> 4) * 8;
        bf16x8 af[8];
#pragma unroll
        for (int kb = 0; kb < 4; ++kb) {
          af[kb]     = *(const bf16x8*)(hbf + ar * HBS + kb * 32 + ac);
          af[kb + 4] = *(const bf16x8*)(hbf + (ar + 16) * HBS + kb * 32 + ac);
        }
#pragma unroll
        for (int i = 0; i < 6; ++i) {
          int nt = w + 4 * i;
          const u16* Bp = qkvW + (size_t)nt * 2048 + lane * 8;
          float bb = bqkv_i[nt * 16 + ar];
          if (i < 2) bb *= 0.25f;                // Q bias scaled like folded W
          f32x4 bi = {bb, bb, bb, bb};
          acc[i][0] = bi; acc[i][1] = bi;
#pragma unroll
          for (int kb = 0; kb < 4; ++kb) {
            bf16x8 b = *(const bf16x8*)(Bp + kb * 512);
            acc[i][0] = MFMA16(af[kb], b, acc[i][0], 0, 0, 0);
            acc[i][1] = MFMA16(af[kb + 4], b, acc[i][1], 0, 0, 0);
          }
        }
      }
#pragma unroll
      for (int i = 0; i < 6; ++i) {
        int nt = w + 4 * i;                 // i<2: Q(nt 0-7); i<4: K(8-15); else V(16-23)
        if (i < 2) {                        // Q: qbuf[h][q][d]
          u16* qb = qbuf + nt * 512 + cr;
#pragma unroll
          for (int j = 0; j < 4; ++j) {
            qb[(rq + j) * 16]      = f2b(acc[i][0][j]);
            qb[(rq + j + 16) * 16] = f2b(acc[i][1][j]);
          }
        } else if (i < 4) {                 // K: kbuf[h][k][d]
          u16* kb = kbuf + (nt - 8) * 512 + cr;
#pragma unroll
          for (int j = 0; j < 4; ++j) {
            kb[(rq + j) * 16]      = f2b(acc[i][0][j]);
            kb[(rq + j + 16) * 16] = f2b(acc[i][1][j]);
          }
        } else {                            // V transposed: vbuf[h][d][k], padded stride
          u32* vb = vbuf_w + (nt - 16) * 320 + cr * 20 + (rq >> 1);
          vb[0] = pk2(acc[i][0][0], acc[i][0][1]);
          vb[1] = pk2(acc[i][0][2], acc[i][0][3]);
          vb[8] = pk2(acc[i][1][0], acc[i][1][1]);
          vb[9] = pk2(acc[i][1][2], acc[i][1][3]);
        }
      }
    }
    __syncthreads();

    // ---- attention (MFMA): wave w owns heads {2w, 2w+1} ----
    {
      const int l15 = lane & 15, gl = lane >> 4;
      const int bpa_base = (l15 + ((gl & 1) << 5)) << 2;   // src_lane*4 base
      const f32x4 z = {0.f, 0.f, 0.f, 0.f};
#pragma unroll
      for (int hi = 0; hi < 2; ++hi) {
        const int h = 2 * w + hi;
        const u16* qb = qbuf + h * 512;
        const u16* kb = kbuf + h * 512;
        bf16x8 vf = *(const bf16x8*)(vbuf + h * 640 + l15 * VST + gl * 8);
        bf16x8 kf0 = {}, kf1 = {};
        if (gl < 2) {     // zero-padded K dimension: only d'=0..15 is real
          kf0 = *(const bf16x8*)(kb + l15 * 16 + gl * 8);
          kf1 = *(const bf16x8*)(kb + (16 + l15) * 16 + gl * 8);
        }
#pragma unroll
        for (int qt = 0; qt < 2; ++qt) {
          bf16x8 qf = {};
          if (gl < 2) qf = *(const bf16x8*)(qb + (qt * 16 + l15) * 16 + gl * 8);
          // S^T tiles: rows=keys, cols=queries (scale folded into Q weights)
          f32x4 s0 = MFMA16(kf0, qf, z, 0, 0, 0);    // keys 0-15
          f32x4 s1 = MFMA16(kf1, qf, z, 0, 0, 0);    // keys 16-31
          float mx = fmaxf(fmaxf(fmaxf(s0[0], s0[1]), fmaxf(s0[2], s0[3])),
                           fmaxf(fmaxf(s1[0], s1[1]), fmaxf(s1[2], s1[3])));
          mx = fmaxf(mx, __shfl_xor(mx, 16));
          mx = fmaxf(mx, __shfl_xor(mx, 32));
          float p0 = __expf(s0[0] - mx), p1 = __expf(s0[1] - mx);
          float p2 = __expf(s0[2] - mx), p3 = __expf(s0[3] - mx);
          float p4 = __expf(s1[0] - mx), p5 = __expf(s1[1] - mx);
          float p6 = __expf(s1[2] - mx), p7 = __expf(s1[3] - mx);
          float sum = ((p0 + p1) + (p2 + p3)) + ((p4 + p5) + (p6 + p7));
          sum += __shfl_xor(sum, 16);
          sum += __shfl_xor(sum, 32);
          float inv = 1.f / sum;
          u32 pw0 = pk2(p0 * inv, p1 * inv), pw1 = pk2(p2 * inv, p3 * inv);
          u32 pw2 = pk2(p4 * inv, p5 * inv), pw3 = pk2(p6 * inv, p7 * inv);
          // build PV A-frag: lane needs P[q=l15][k=8*gl+jj] via bpermute
          union { u32 uw[4]; bf16x8 v; } pa;
#pragma unroll
          for (int ww = 0; ww < 4; ++ww) {
            int addr = bpa_base + ((ww >> 1) << 6);
            u32 lo = __builtin_amdgcn_ds_bpermute(addr, (int)((ww & 1) ? pw1 : pw0));
            u32 hi2 = __builtin_amdgcn_ds_bpermute(addr, (int)((ww & 1) ? pw3 : pw2));
            pa.uw[ww] = (gl < 2) ? lo : hi2;
          }
          f32x4 o = MFMA16(pa.v, vf, z, 0, 0, 0);    // O[q 16][d 16], full K=32
#pragma unroll
          for (int j = 0; j < 4; ++j)
            hbf[(qt * 16 + gl * 4 + j) * HBS + h * 16 + l15] = f2b(o[j]);
        }
      }
    }
    __syncthreads();

    // ---- proj: attn_out(bf16) @ Wo -> xs += ----
    {
      f32x4 acc[2][2];
      gemm_kt4_b<2>(hbf, HBS, oW, w, lane, bo_i, acc);
#pragma unroll
      for (int i = 0; i < 2; ++i) {
        int n = (w + 4 * i) * 16 + cr;
#pragma unroll
        for (int j = 0; j < 4; ++j) {
          xs[(rq + j) * LST + n]      += acc[i][0][j];
          xs[(rq + j + 16) * LST + n] += acc[i][1][j];
        }
      }
    }
    __syncthreads();

    layer_norm_bf(xs, hbf, a.ln2s + li * NE, a.ln2b + li * NE, t, mrow, vrow);

    // ---- MLP, K-chunked (2 x 256 cols) ----
    {
      f32x4 acc2[2][2];
#pragma unroll
      for (int i = 0; i < 2; ++i) {
        float bb = bm2_i[(w + 4 * i) * 16 + cr];
        f32x4 bi = {bb, bb, bb, bb};
        acc2[i][0] = bi; acc2[i][1] = bi;
      }
#pragma unroll
      for (int ch = 0; ch < 2; ++ch) {
        {
          f32x4 acc[4][2];
          gemm_kt4_b<4>(hbf, HBS, m1W + ch * 32768, w, lane, bm1_i + ch * 256, acc);
#pragma unroll
          for (int i = 0; i < 4; ++i) {
            int nl = (w + 4 * i) * 16 + cr;
#pragma unroll
            for (int j = 0; j < 4; ++j) {
              h1c[(rq + j) * H1C + nl]      = f2b(gelu_f(acc[i][0][j]));
              h1c[(rq + j + 16) * H1C + nl] = f2b(gelu_f(acc[i][1][j]));
            }
          }
        }
        __syncthreads();
        gemm_kt8_acc(h1c, m2W, ch * 8, w, lane, acc2);
        __syncthreads();
      }
#pragma unroll
      for (int i = 0; i < 2; ++i) {
        int n = (w + 4 * i) * 16 + cr;
#pragma unroll
        for (int j = 0; j < 4; ++j) {
          xs[(rq + j) * LST + n]      += acc2[i][0][j];
          xs[(rq + j + 16) * LST + n] += acc2[i][1][j];
        }
      }
    }
    __syncthreads();
  }

  // ---- final LN -> hbf ----
  layer_norm_bf(xs, hbf, a.lnfs, a.lnfb, t, mrow, vrow);

  // preload Wd2 f32 (region disjoint from h1c; ordered by the d1 barrier)
  for (int i = t; i < 1024; i += 256) wd2s[i] = a.Wd2[i];

  // ---- decoder, K-chunked ----
  float yacc = 0.f;
  const int pdec = t >> 3, dd2 = (t >> 2) & 1, q4 = t & 3;
#pragma unroll
  for (int ch = 0; ch < 2; ++ch) {
    {
      f32x4 acc[4][2];
      gemm_kt4_b<4>(hbf, HBS, wsW + D1_W_OFF + ch * 32768, w, lane, a.bd1 + ch * 256, acc);
#pragma unroll
      for (int i = 0; i < 4; ++i) {
        int nl = (w + 4 * i) * 16 + cr;
#pragma unroll
        for (int j = 0; j < 4; ++j) {
          h1c[(rq + j) * H1C + nl]      = f2b(fmaxf(acc[i][0][j], 0.f));
          h1c[(rq + j + 16) * H1C + nl] = f2b(fmaxf(acc[i][1][j], 0.f));
        }
      }
    }
    __syncthreads();
    {
      const u16* hrow = h1c + pdec * H1C + q4 * 64;
      const float* wp = wd2s + (ch * 256 + q4 * 64) * 2 + dd2;
#pragma unroll
      for (int k8 = 0; k8 < 8; ++k8) {
        bf16x8 hv = *(const bf16x8*)(hrow + k8 * 8);
#pragma unroll
        for (int jj = 0; jj < 8; ++jj)
          yacc += b2f((u16)hv[jj]) * wp[(k8 * 8 + jj) * 2];
      }
    }
    __syncthreads();
  }

  // ---- y write + loss partial ----
  {
    yacc += __shfl_xor(yacc, 1);
    yacc += __shfl_xor(yacc, 2);
    if (q4 == 0) {
      float y = yacc + a.bd2[dd2];
      a.out[1 + (s * NP + pdec) * 2 + dd2] = y;
      float lnm = a.pos[(s * NP + pdec) * 2 + dd2] - (dd2 ? cy : cx);
      float d = y - lnm;
      if (selv[pdec] != 0) atomicAdd(&lacc, d * d);
    }
  }
  __syncthreads();
  if (t == 0) {
    atomicAdd(a.wsf, lacc);
    int cnt = 0;
#pragma unroll
    for (int p = 0; p < NP; ++p) cnt += (selv[p] != 0) ? 1 : 0;
    atomicAdd(a.wsi, cnt);
  }
}

__global__ void mrm_fin(const float* ws, float* out) {
  float num = ws[0];
  int cnt = ((const int*)ws)[1];
  float den = fmaxf((float)cnt * 2.0f, 1.0f);
  out[0] = num / den;
}

extern "C" void kernel_launch(void* const* d_in, const int* in_sizes, int n_in,
                              void* d_out, int out_size, void* d_ws, size_t ws_size,
                              hipStream_t stream) {
  (void)in_sizes; (void)n_in; (void)out_size; (void)ws_size;
  Args a;
  a.pos   = (const float*)d_in[0];
  a.ctr   = (const float*)d_in[1];
  a.ang   = (const float*)d_in[2];
  a.sel   = (const int*)d_in[4];
  a.Wp    = (const float*)d_in[5];
  a.bp    = (const float*)d_in[6];
  a.Wpe1  = (const float*)d_in[7];
  a.bpe1  = (const float*)d_in[8];
  a.Wpe2  = (const float*)d_in[9];
  a.bpe2  = (const float*)d_in[10];
  a.ltype = (const float*)d_in[11];
  a.mtok  = (const float*)d_in[12];
  a.Wqkv  = (const float*)d_in[13];
  a.bqkv  = (const float*)d_in[14];
  a.Wo    = (const float*)d_in[15];
  a.bo    = (const float*)d_in[16];
  a.ln1s  = (const float*)d_in[17];
  a.ln1b  = (const float*)d_in[18];
  a.Wm1   = (const float*)d_in[19];
  a.bm1   = (const float*)d_in[20];
  a.Wm2   = (const float*)d_in[21];
  a.bm2   = (const float*)d_in[22];
  a.ln2s  = (const float*)d_in[23];
  a.ln2b  = (const float*)d_in[24];
  a.lnfs  = (const float*)d_in[25];
  a.lnfb  = (const float*)d_in[26];
  a.Wd1   = (const float*)d_in[27];
  a.bd1   = (const float*)d_in[28];
  a.Wd2   = (const float*)d_in[29];
  a.bd2   = (const float*)d_in[30];
  a.out   = (float*)d_out;
  a.wsf   = (float*)d_ws;
  a.wsi   = ((int*)d_ws) + 1;

  hipMemsetAsync(d_ws, 0, 8, stream);
  u16* wsW = (u16*)((char*)d_ws + 64);
  pack_w<<<dim3(96),  dim3(256), 0, stream>>>(a.Wqkv, wsW + QKV_W_OFF, 128, 384, 4, 128, 0.25f);
  pack_w<<<dim3(32),  dim3(256), 0, stream>>>(a.Wo,   wsW + O_W_OFF,   128, 128, 4, 0, 1.f);
  pack_w<<<dim3(128), dim3(256), 0, stream>>>(a.Wm1,  wsW + M1_W_OFF,  128, 512, 4, 0, 1.f);
  pack_w<<<dim3(128), dim3(256), 0, stream>>>(a.Wm2,  wsW + M2_W_OFF,  512, 128, 4, 0, 1.f);
  pack_w<<<dim3(32),  dim3(256), 0, stream>>>(a.Wd1,  wsW + D1_W_OFF,  128, 512, 1, 0, 1.f);
  mrm_main_mfma<<<dim3(NSEQ), dim3(256), 0, stream>>>(a, wsW);
  mrm_fin<<<dim3(1), dim3(1), 0, stream>>>((const float*)d_ws, (float*)d_out);
}